// Round 5
// baseline (397.353 us; speedup 1.0000x reference)
//
#include <hip/hip_runtime.h>
#include <hip/hip_bf16.h>

using bf16 = __hip_bfloat16;
typedef short bf16x8 __attribute__((ext_vector_type(8)));
typedef float f32x4 __attribute__((ext_vector_type(4)));
typedef unsigned short ushort8_t __attribute__((ext_vector_type(8)));
typedef unsigned uint4_t __attribute__((ext_vector_type(4)));
typedef unsigned long long u64;

static constexpr int NA_ = 2048, NB_ = 2048;
static constexpr int H_ = 8, DH_ = 64, INNER_ = 512;
static constexpr int MROWS = 2 * NA_;  // 4096 rows for both batches

#define MFMA32(a, b, c) __builtin_amdgcn_mfma_f32_16x16x32_bf16(a, b, c, 0, 0, 0)

#if __has_builtin(__builtin_amdgcn_exp2f)
#define EXP2(x) __builtin_amdgcn_exp2f(x)
#else
#define EXP2(x) exp2f(x)
#endif

__device__ __forceinline__ unsigned short bfbits(float x) {
  bf16 h = __float2bfloat16(x);
  return __builtin_bit_cast(unsigned short, h);
}
__device__ __forceinline__ float b2f(unsigned short u) {
  unsigned v = ((unsigned)u) << 16;
  return __builtin_bit_cast(float, v);
}

// pack two fp32 -> dword of 2 bf16 (lo=a, hi=b), round-half-up via +0x8000
__device__ __forceinline__ unsigned pkbf(float a, float b) {
  unsigned ua = __builtin_bit_cast(unsigned, a) + 0x8000u;
  unsigned ub = __builtin_bit_cast(unsigned, b) + 0x8000u;
#if __has_builtin(__builtin_amdgcn_perm)
  // d = [ua.b2, ua.b3, ub.b2, ub.b3]
  return __builtin_amdgcn_perm(ub, ua, 0x07060302u);
#else
  return (ua >> 16) | (ub & 0xFFFF0000u);
#endif
}

// ======== prep: ln_feat (blocks 0..2047) | wconv (2048..4607) | maskpack (4608..6655)
__global__ __launch_bounds__(256) void prep_kernel(
    const float* __restrict__ fa_in, const float* __restrict__ fb_in,
    const float* __restrict__ law, const float* __restrict__ lab,
    const float* __restrict__ lbw, const float* __restrict__ lbb,
    bf16* __restrict__ fa, bf16* __restrict__ fb,
    const float* __restrict__ Wq, const float* __restrict__ Wk,
    const float* __restrict__ Wv, const float* __restrict__ Wg,
    const float* __restrict__ Wo,
    bf16* __restrict__ Wqt, bf16* __restrict__ Wkt,
    bf16* __restrict__ Wvt, bf16* __restrict__ Wgt,
    bf16* __restrict__ Woth, bf16* __restrict__ Wotl,
    const void* __restrict__ maskp, u64* __restrict__ mbits,
    unsigned* __restrict__ flags) {
  int blk = blockIdx.x;
  int t = threadIdx.x;
  if (blk < 2048) {
    // ---- LN of feats, one wave per row ----
    int row = blk * 4 + (t >> 6);
    int lane = t & 63;
    const float *src, *w, *bb;
    bf16* dst;
    int r;
    if (row < MROWS) { src = fa_in; w = law; bb = lab; dst = fa; r = row; }
    else             { src = fb_in; w = lbw; bb = lbb; dst = fb; r = row - MROWS; }
    float4 x = *(const float4*)(src + (size_t)r * 256 + lane * 4);
    float s  = (x.x + x.y) + (x.z + x.w);
    float s2 = (x.x * x.x + x.y * x.y) + (x.z * x.z + x.w * x.w);
#pragma unroll
    for (int m = 32; m >= 1; m >>= 1) { s += __shfl_xor(s, m); s2 += __shfl_xor(s2, m); }
    float mean = s * (1.0f / 256.0f);
    float var  = s2 * (1.0f / 256.0f) - mean * mean;
    float rstd = rsqrtf(var + 1e-5f);
    float4 wv = *(const float4*)(w + lane * 4);
    float4 bv = *(const float4*)(bb + lane * 4);
    ushort4 o;
    o.x = bfbits((x.x - mean) * rstd * wv.x + bv.x);
    o.y = bfbits((x.y - mean) * rstd * wv.y + bv.y);
    o.z = bfbits((x.z - mean) * rstd * wv.z + bv.z);
    o.w = bfbits((x.w - mean) * rstd * wv.w + bv.w);
    *(ushort4*)(dst + (size_t)r * 256 + lane * 4) = o;
  } else if (blk < 4608) {
    // ---- weight convert/transpose ----
    int z = (blk - 2048) >> 9;
    int idx = ((blk - 2048) & 511) * 256 + t;  // 0..131071
    if (z < 4) {
      const float* W = (z == 0) ? Wq : (z == 1) ? Wk : (z == 2) ? Wv : Wg;
      bf16* Wt = (z == 0) ? Wqt : (z == 1) ? Wkt : (z == 2) ? Wvt : Wgt;
      int kk = idx >> 9, n = idx & 511;
      Wt[n * 256 + kk] = __float2bfloat16(W[idx]);
    } else {
      int kk = idx >> 8, n = idx & 255;
      float w = Wo[idx];
      bf16 hi = __float2bfloat16(w);
      Woth[n * 512 + kk] = hi;
      Wotl[n * 512 + kk] = __float2bfloat16(w - __bfloat162float(hi));
    }
  } else {
    // ---- zero merge flags for attn (re-done every launch; ws is poisoned) ----
    if (blk - 4608 < 2) flags[(blk - 4608) * 256 + t] = 0u;
    // ---- mask bit-pack with per-block dtype self-detect ----
    __shared__ unsigned shf[4];
    const unsigned char* mu = (const unsigned char*)maskp;
    bool nz = ((t & 3) != 0) && (mu[t] != 0);
    u64 bal = __ballot(nz);
    if ((t & 63) == 0) shf[t >> 6] = (bal != 0ull) ? 1u : 0u;
    __syncthreads();
    bool m8 = (shf[0] | shf[1] | shf[2] | shf[3]) != 0;  // nonzero off-4 byte => u8
    int lane = t & 63, wid = t >> 6;
    int lb = blk - 4608;
    for (size_t word = (size_t)lb * 4 + wid; word < 131072; word += 8192) {
      size_t e = word * 64 + lane;
      int v = m8 ? (int)mu[e] : ((const int*)maskp)[e];
      u64 b2 = __ballot(v != 0);
      if (lane == 0) mbits[word] = b2;
    }
  }
}

// ======== all four pre-GEMMs in one launch: grid dim3(256,1,4) ========
// z=0: q = LN(fa@Wq+bq) * scale2 (attn scale folded in!)  z=1: k = LN(fb@Wk+bk)
// z=2: g = fa@Wg+bg (bf16 [M][512])  z=3: v^T layout (m-tile 128, n-tile 64)
__global__ __launch_bounds__(256) void gemm4_kernel(
    const bf16* __restrict__ fa, const bf16* __restrict__ fb,
    const bf16* __restrict__ Wqt, const bf16* __restrict__ Wkt,
    const bf16* __restrict__ Wgt, const bf16* __restrict__ Wvt,
    const float* __restrict__ bq, const float* __restrict__ bk,
    const float* __restrict__ bg, const float* __restrict__ bv,
    const float* __restrict__ qlw, const float* __restrict__ qlb,
    const float* __restrict__ klw, const float* __restrict__ klb,
    bf16* __restrict__ qo, bf16* __restrict__ ko,
    bf16* __restrict__ gout, bf16* __restrict__ vout) {
  __shared__ __align__(16) char sm[27648];
  int z = blockIdx.z;
  int t = threadIdx.x, wave = t >> 6, lane = t & 63;
  int lm = lane & 15, quad = lane >> 4, q8 = quad * 8;

  if (z < 2) {
    // ---------- q/k GEMM with fused LayerNorm ----------
    bf16* As = (bf16*)sm;                       // [16][264] = 8448 B
    float* Pred = (float*)(sm + 16896);         // [16][8]
    float* MV   = (float*)(sm + 17408);         // [16][2]
    const bf16* A    = z ? fb : fa;
    const bf16* Wt   = z ? Wkt : Wqt;
    const float* bias = z ? bk : bq;
    const float* lw  = z ? klw : qlw;
    const float* lb  = z ? klb : qlb;
    bf16* out        = z ? ko : qo;
    int m0 = blockIdx.x * 16;
    // stage A 16x256 (stride 264 B-aligned 16)
#pragma unroll
    for (int i = 0; i < 2; i++) {
      int id = t + 256 * i, r = id >> 5, cg = id & 31;
      *(ushort8_t*)(&As[r * 264 + cg * 8]) =
          *(const ushort8_t*)(A + (size_t)(m0 + r) * 256 + cg * 8);
    }
    __syncthreads();
    int n0w = wave * 128;
    f32x4 acc[8] = {};
    const bf16* wrow[8];
#pragma unroll
    for (int ni = 0; ni < 8; ni++) wrow[ni] = Wt + (size_t)(n0w + ni * 16 + lm) * 256;
#pragma unroll
    for (int ks = 0; ks < 8; ks++) {
      int k0 = ks * 32;
      bf16x8 af = *(const bf16x8*)(&As[lm * 264 + k0 + q8]);
#pragma unroll
      for (int ni = 0; ni < 8; ni++) {
        bf16x8 bf_ = *(const bf16x8*)(wrow[ni] + k0 + q8);
        acc[ni] = MFMA32(af, bf_, acc[ni]);
      }
    }
    float bvv[8];
#pragma unroll
    for (int ni = 0; ni < 8; ni++) bvv[ni] = bias[n0w + ni * 16 + lm];
#pragma unroll
    for (int ni = 0; ni < 8; ni++)
#pragma unroll
      for (int r = 0; r < 4; r++) acc[ni][r] += bvv[ni];
    // per-row stats over the wave's 128 cols
#pragma unroll
    for (int r = 0; r < 4; r++) {
      float s = 0.f, s2 = 0.f;
#pragma unroll
      for (int ni = 0; ni < 8; ni++) { s += acc[ni][r]; s2 += acc[ni][r] * acc[ni][r]; }
#pragma unroll
      for (int m = 1; m <= 8; m <<= 1) { s += __shfl_xor(s, m); s2 += __shfl_xor(s2, m); }
      if (lm == 0) {
        int row = quad * 4 + r;
        Pred[row * 8 + wave * 2]     = s;
        Pred[row * 8 + wave * 2 + 1] = s2;
      }
    }
    __syncthreads();
    if (t < 16) {
      float s = 0.f, s2 = 0.f;
#pragma unroll
      for (int w = 0; w < 4; w++) { s += Pred[t * 8 + w * 2]; s2 += Pred[t * 8 + w * 2 + 1]; }
      float mean = s * (1.0f / 512.0f);
      float var  = s2 * (1.0f / 512.0f) - mean * mean;
      MV[t * 2]     = mean;
      MV[t * 2 + 1] = rsqrtf(var + 1e-5f);
    }
    __syncthreads();
    float lww[8], lbb_[8];
#pragma unroll
    for (int ni = 0; ni < 8; ni++) {
      lww[ni]  = lw[n0w + ni * 16 + lm];
      lbb_[ni] = lb[n0w + ni * 16 + lm];
    }
    if (z == 0) {
      // fold attn scale (1/sqrt(dh) * log2(e)) into q so attn does p=exp2(s) raw
      const float SC = 0.125f * 1.44269504088896f;
#pragma unroll
      for (int ni = 0; ni < 8; ni++) { lww[ni] *= SC; lbb_[ni] *= SC; }
    }
#pragma unroll
    for (int r = 0; r < 4; r++) {
      int row = quad * 4 + r;
      float mean = MV[row * 2], rstd = MV[row * 2 + 1];
      size_t obase = (size_t)(m0 + row) * 512 + n0w;
#pragma unroll
      for (int ni = 0; ni < 8; ni++)
        out[obase + ni * 16 + lm] =
            __float2bfloat16((acc[ni][r] - mean) * rstd * lww[ni] + lbb_[ni]);
    }
  } else {
    // ---------- g/v GEMM: m-tile 128, n-tile 64 (stride 72, 16-B aligned) ----------
    bf16* As = (bf16*)sm;                 // [128][72] = 18432 B
    bf16* Bs = (bf16*)(sm + 18432);       // [64][72]  = 9216 B
    const bf16* A    = (z == 3) ? fb : fa;
    const bf16* Wt   = (z == 3) ? Wvt : Wgt;
    const float* bias = (z == 3) ? bv : bg;
    int x = blockIdx.x;
    int m0 = (x >> 3) * 128, n0 = (x & 7) * 64;
    int wm = wave * 32;
    f32x4 acc[2][4] = {};
    for (int k0 = 0; k0 < 256; k0 += 64) {
      __syncthreads();
#pragma unroll
      for (int i = 0; i < 4; i++) {
        int id = t + 256 * i, r = id >> 3, cg = id & 7;
        *(ushort8_t*)(&As[r * 72 + cg * 8]) =
            *(const ushort8_t*)(A + (size_t)(m0 + r) * 256 + k0 + cg * 8);
      }
#pragma unroll
      for (int i = 0; i < 2; i++) {
        int id = t + 256 * i, r = id >> 3, cg = id & 7;
        *(ushort8_t*)(&Bs[r * 72 + cg * 8]) =
            *(const ushort8_t*)(Wt + (size_t)(n0 + r) * 256 + k0 + cg * 8);
      }
      __syncthreads();
#pragma unroll
      for (int kk = 0; kk < 64; kk += 32) {
        bf16x8 af[2], bf_[4];
#pragma unroll
        for (int mi = 0; mi < 2; mi++)
          af[mi] = *(const bf16x8*)(&As[(wm + mi * 16 + lm) * 72 + kk + q8]);
#pragma unroll
        for (int ni = 0; ni < 4; ni++)
          bf_[ni] = *(const bf16x8*)(&Bs[(ni * 16 + lm) * 72 + kk + q8]);
#pragma unroll
        for (int mi = 0; mi < 2; mi++)
#pragma unroll
          for (int ni = 0; ni < 4; ni++)
            acc[mi][ni] = MFMA32(af[mi], bf_[ni], acc[mi][ni]);
      }
    }
    if (z == 2) {
#pragma unroll
      for (int mi = 0; mi < 2; mi++)
#pragma unroll
        for (int ni = 0; ni < 4; ni++) {
          int nn = n0 + ni * 16 + lm;
          float bvv = bias[nn];
          int mb = m0 + wm + mi * 16 + quad * 4;
#pragma unroll
          for (int r = 0; r < 4; r++)
            gout[(size_t)(mb + r) * 512 + nn] = __float2bfloat16(acc[mi][ni][r] + bvv);
        }
    } else {
      // v^T: bounce through LDS [64 d][136] for coalesced [d][j] write
      __syncthreads();
      bf16* buf = (bf16*)sm;
#pragma unroll
      for (int mi = 0; mi < 2; mi++)
#pragma unroll
        for (int ni = 0; ni < 4; ni++) {
          int d_local = ni * 16 + lm;
          float bvv = bias[n0 + d_local];
          int j_local = wm + mi * 16 + quad * 4;
#pragma unroll
          for (int r = 0; r < 4; r++)
            buf[d_local * 136 + j_local + r] = __float2bfloat16(acc[mi][ni][r] + bvv);
        }
      __syncthreads();
      int bidx2 = m0 >> 11, j0g = m0 & 2047, hh = n0 >> 6;
      int dl = t >> 2, jseg = (t & 3) * 32;
      bf16* dstrow = vout + (size_t)((bidx2 * 8 + hh) * 64 + dl) * 2048 + j0g + jseg;
#pragma unroll
      for (int c = 0; c < 4; c++)
        *(ushort8_t*)(dstrow + c * 8) = *(const ushort8_t*)(&buf[dl * 136 + jseg + c * 8]);
    }
  }
}

// ---------------- flash attention: 32-i waves + j-half split + atomic merge ------
// grid dim3(32,16,2): (qt 64-row tile, bh, jh j-half). Block 256 thr, 4 waves =
// (wj in {0,1}: 32-j slice) x (wi in {0,1}: 32-i rows). Q in REGISTERS from
// global (no Q LDS). LDS = K/V double-buffer only -> 37.4 KB -> 4 blocks/CU,
// 16 waves/CU; LDS ops per output HALVED vs 16-i waves. 16 iters of 64 j.
// K sigma-permuted per 32-row group -> QK^T C-regs pack into k32 PV A-frag.
// Each block -> partial O (64x64 f32) + partial l to workspace; SECOND
// finisher of each (qt,bh) pair (atomicAdd flag; fenced) merges, applies
// 1/l * sigmoid(g), writes gh/gl. fid mapping puts partners on same XCD.
__global__ __launch_bounds__(256, 4) void attn_kernel(
    const bf16* __restrict__ q, const bf16* __restrict__ k,
    const bf16* __restrict__ vt, const bf16* __restrict__ g,
    const u64* __restrict__ mbits,
    float* __restrict__ opart, float* __restrict__ lpart,
    unsigned* __restrict__ flags,
    bf16* __restrict__ gh, bf16* __restrict__ gl) {
  __shared__ __align__(16) char smem[37408];
  bf16* KVB = (bf16*)smem;               // 2 bufs x (K 64*72 + V 64*72) = 36864 B
  float* Om = (float*)smem;              // post-loop overlay: 64*66*4 = 16896 B
  float* Lbuf = (float*)(smem + 36864);  // 2 wj x 64 = 512 B
  unsigned* sflag = (unsigned*)(smem + 37376);
  constexpr int BUFE = 2 * 64 * 72;      // elems per dbuf slot (K+V)

  // fid -> (bh, qt, jh): bits [2:0] XCD-class carries bh-high so each XCD owns
  // 2 whole bh; partners (jh 0/1) share all low bits -> same XCD.
  int fid = blockIdx.x + 32 * blockIdx.y + 512 * blockIdx.z;
  int bh = (fid & 7) * 2 + ((fid >> 3) & 1);
  int qt = (fid >> 4) & 31;
  int jh = fid >> 9;
  int bidx = bh >> 3, h = bh & 7;
  int i0 = qt * 64;
  int pair = bh * 32 + qt;               // 0..511
  int t = threadIdx.x, wave = t >> 6, lane = t & 63;
  int wj = wave >> 1, wi = wave & 1;
  int lm = lane & 15, quad = lane >> 4, q8 = quad * 8;
  int wj32 = wj * 32, wi32 = wi * 32;
  int srow = t >> 3, scg = (t & 7) * 8;  // staging: rows srow/srow+32, 8 cols x8

  // sigma-permuted K staging rows (within each 32-row group)
  int ksrow = ((srow & 4) << 2) | ((srow & 24) >> 1) | (srow & 3);
  int ksl0 = ksrow * 72 + scg;
  int ksl1 = (ksrow + 32) * 72 + scg;
  int vsl0 = srow * 72 + scg;
  int vsl1 = (srow + 32) * 72 + scg;

  const bf16* kb = k + (size_t)(bidx * NB_) * INNER_ + h * DH_;
  const bf16* vb = vt + (size_t)(bh * DH_) * NB_;
  const bf16* ksrc0 = kb + (size_t)(jh * 1024 + srow) * INNER_ + scg;
  const bf16* ksrc1 = kb + (size_t)(jh * 1024 + srow + 32) * INNER_ + scg;
  const bf16* vsrc0 = vb + (size_t)srow * NB_ + jh * 1024 + scg;
  const bf16* vsrc1 = vb + (size_t)(srow + 32) * NB_ + jh * 1024 + scg;

  // Q fragments directly from global (one-time; 4 x 16B per lane)
  const bf16* qbase = q + (size_t)(bidx * NA_ + i0 + wi32 + lm) * INNER_ + h * DH_;
  bf16x8 bq00 = *(const bf16x8*)(qbase + q8);
  bf16x8 bq01 = *(const bf16x8*)(qbase + 32 + q8);
  bf16x8 bq10 = *(const bf16x8*)(qbase + 16 * INNER_ + q8);
  bf16x8 bq11 = *(const bf16x8*)(qbase + 16 * INNER_ + 32 + q8);

  // constant B fragment: ones-column at n=0 (bf16 1.0 = 0x3F80)
  bf16x8 bone;
  {
    short onev = (lm == 0) ? (short)0x3F80 : (short)0;
#pragma unroll
    for (int i = 0; i < 8; i++) bone[i] = onev;
  }

  f32x4 oacc[2][4] = {};
  f32x4 lacc[2] = {};

  const u64* mrp0 = mbits + (size_t)(bidx * NA_ + i0 + wi32 + lm) * (NB_ / 64) + jh * 16;
  const u64* mrp1 = mrp0 + (size_t)16 * (NB_ / 64);
  int shp = wj32 + quad * 8;

  // prologue: tile0 -> buf0; tile1 -> regs
  ushort8_t kr0 = *(const ushort8_t*)(ksrc0);
  ushort8_t kr1 = *(const ushort8_t*)(ksrc1);
  ushort8_t vr0 = *(const ushort8_t*)(vsrc0);
  ushort8_t vr1 = *(const ushort8_t*)(vsrc1);
  *(ushort8_t*)(&KVB[ksl0]) = kr0;
  *(ushort8_t*)(&KVB[ksl1]) = kr1;
  *(ushort8_t*)(&KVB[64 * 72 + vsl0]) = vr0;
  *(ushort8_t*)(&KVB[64 * 72 + vsl1]) = vr1;
  kr0 = *(const ushort8_t*)(ksrc0 + 64 * INNER_);
  kr1 = *(const ushort8_t*)(ksrc1 + 64 * INNER_);
  vr0 = *(const ushort8_t*)(vsrc0 + 64);
  vr1 = *(const ushort8_t*)(vsrc1 + 64);
  u64 smw0 = mrp0[0] >> shp;
  u64 smw1 = mrp1[0] >> shp;
  __syncthreads();  // buf0 ready

  for (int it = 0; it < 16; it++) {
    bf16* Ks = KVB + (it & 1) * BUFE;
    bf16* Vs = Ks + 64 * 72;
    // write next tile into alt buffer (off critical path)
    if (it < 15) {
      bf16* Kn = KVB + ((it + 1) & 1) * BUFE;
      *(ushort8_t*)(&Kn[ksl0]) = kr0;
      *(ushort8_t*)(&Kn[ksl1]) = kr1;
      *(ushort8_t*)(&Kn[64 * 72 + vsl0]) = vr0;
      *(ushort8_t*)(&Kn[64 * 72 + vsl1]) = vr1;
    }
    // issue global loads 2 tiles ahead
    if (it < 14) {
      kr0 = *(const ushort8_t*)(ksrc0 + (size_t)(it + 2) * (64 * INNER_));
      kr1 = *(const ushort8_t*)(ksrc1 + (size_t)(it + 2) * (64 * INNER_));
      vr0 = *(const ushort8_t*)(vsrc0 + (it + 2) * 64);
      vr1 = *(const ushort8_t*)(vsrc1 + (it + 2) * 64);
    }
    u64 nm0 = smw0, nm1 = smw1;
    if (it < 15) {
      nm0 = mrp0[it + 1] >> shp;
      nm1 = mrp1[it + 1] >> shp;
    }

    // QK^T: wave's 32-j slice (sigma-permuted rows) x 32 i
    bf16x8 a00 = *(const bf16x8*)(&Ks[(wj32 + lm) * 72 + q8]);
    bf16x8 a01 = *(const bf16x8*)(&Ks[(wj32 + lm) * 72 + 32 + q8]);
    bf16x8 a10 = *(const bf16x8*)(&Ks[(wj32 + 16 + lm) * 72 + q8]);
    bf16x8 a11 = *(const bf16x8*)(&Ks[(wj32 + 16 + lm) * 72 + 32 + q8]);
    f32x4 st00 = {0.f, 0.f, 0.f, 0.f}, st01 = {0.f, 0.f, 0.f, 0.f};
    f32x4 st10 = {0.f, 0.f, 0.f, 0.f}, st11 = {0.f, 0.f, 0.f, 0.f};
    st00 = MFMA32(a00, bq00, st00); st00 = MFMA32(a01, bq01, st00);
    st01 = MFMA32(a10, bq00, st01); st01 = MFMA32(a11, bq01, st01);
    st10 = MFMA32(a00, bq10, st10); st10 = MFMA32(a01, bq11, st10);
    st11 = MFMA32(a10, bq10, st11); st11 = MFMA32(a11, bq11, st11);

    // p = exp2(masked s); lane's j = wj32 + quad*8 + js*4 + r -> bit js*4+r
    float p00[4], p01[4], p10[4], p11[4];
#pragma unroll
    for (int r = 0; r < 4; r++) {
      p00[r] = EXP2(((smw0 >> r) & 1ull) ? st00[r] : -200.0f);
      p01[r] = EXP2(((smw0 >> (4 + r)) & 1ull) ? st01[r] : -200.0f);
      p10[r] = EXP2(((smw1 >> r) & 1ull) ? st10[r] : -200.0f);
      p11[r] = EXP2(((smw1 >> (4 + r)) & 1ull) ? st11[r] : -200.0f);
    }

    // pack into k32 PV A-fragments (P register-only)
    uint4_t u0, u1;
    u0[0] = pkbf(p00[0], p00[1]);
    u0[1] = pkbf(p00[2], p00[3]);
    u0[2] = pkbf(p01[0], p01[1]);
    u0[3] = pkbf(p01[2], p01[3]);
    u1[0] = pkbf(p10[0], p10[1]);
    u1[1] = pkbf(p10[2], p10[3]);
    u1[2] = pkbf(p11[0], p11[1]);
    u1[3] = pkbf(p11[2], p11[3]);
    bf16x8 pa0 = __builtin_bit_cast(bf16x8, u0);
    bf16x8 pa1 = __builtin_bit_cast(bf16x8, u1);

    // PV: A = P [m=i][k=j32], B = V^T [n=d][k=j] -> O[i][d]
#pragma unroll
    for (int c = 0; c < 4; c++) {
      bf16x8 v_ = *(const bf16x8*)(&Vs[(c * 16 + lm) * 72 + wj32 + q8]);
      oacc[0][c] = MFMA32(pa0, v_, oacc[0][c]);
      oacc[1][c] = MFMA32(pa1, v_, oacc[1][c]);
    }
    lacc[0] = MFMA32(pa0, bone, lacc[0]);
    lacc[1] = MFMA32(pa1, bone, lacc[1]);

    smw0 = nm0;
    smw1 = nm1;
    __syncthreads();
  }

  // -------- in-block wj merge into Om/Lbuf (Om overlays KVB) --------
  if (lm == 0) {
#pragma unroll
    for (int is_ = 0; is_ < 2; is_++)
#pragma unroll
      for (int r = 0; r < 4; r++)
        Lbuf[wj * 64 + wi32 + is_ * 16 + quad * 4 + r] = lacc[is_][r];
  }
  if (wj == 1) {
#pragma unroll
    for (int is_ = 0; is_ < 2; is_++)
#pragma unroll
      for (int c = 0; c < 4; c++)
#pragma unroll
        for (int r = 0; r < 4; r++)
          Om[(wi32 + is_ * 16 + quad * 4 + r) * 66 + c * 16 + lm] = oacc[is_][c][r];
  }
  __syncthreads();
  if (wj == 0) {
#pragma unroll
    for (int is_ = 0; is_ < 2; is_++)
#pragma unroll
      for (int c = 0; c < 4; c++)
#pragma unroll
        for (int r = 0; r < 4; r++)
          Om[(wi32 + is_ * 16 + quad * 4 + r) * 66 + c * 16 + lm] += oacc[is_][c][r];
  }
  __syncthreads();

  // -------- export block partial; second finisher merges --------
  int slot = pair * 2 + jh;
  {
    int row = t >> 2, c0 = (t & 3) * 16;
    float* dst = opart + (size_t)slot * 4096 + row * 64 + c0;
#pragma unroll
    for (int e = 0; e < 4; e++) {
      float4 v4 = *(float4*)(&Om[row * 66 + c0 + e * 4]);
      *(float4*)(dst + e * 4) = v4;
    }
    if (t < 64) lpart[slot * 64 + t] = Lbuf[t] + Lbuf[64 + t];
  }
  __syncthreads();       // all partial stores drained (vmcnt 0 before barrier)
  __threadfence();       // make them device-visible
  if (t == 0) *sflag = atomicAdd(&flags[pair], 1u);
  __syncthreads();
  if (*sflag == 0) return;   // first finisher: partner will merge
  __threadfence();           // acquire partner's stores

  {
    int pslot = pair * 2 + (1 - jh);
    int row = t >> 2, c0 = (t & 3) * 16;
    const float* psrc = opart + (size_t)pslot * 4096 + row * 64 + c0;
    float l = Lbuf[row] + Lbuf[64 + row] + lpart[pslot * 64 + row];
    float inv = 1.0f / l;
    size_t idx = (size_t)(bidx * NA_ + i0 + row) * INNER_ + h * DH_ + c0;
    ushort8_t gv0 = *(const ushort8_t*)(g + idx);
    ushort8_t gv1 = *(const ushort8_t*)(g + idx + 8);
    ushort8_t oh0, ol0, oh1, ol1;
#pragma unroll
    for (int e = 0; e < 8; e++) {
      float o = Om[row * 66 + c0 + e] + psrc[e];
      float gf = b2f((unsigned short)gv0[e]);
      float sig = 1.0f / (1.0f + __expf(-gf));
      float val = o * inv * sig;
      unsigned short hb = bfbits(val);
      oh0[e] = hb;
      ol0[e] = bfbits(val - b2f(hb));
    }
#pragma unroll
    for (int e = 0; e < 8; e++) {
      float o = Om[row * 66 + c0 + 8 + e] + psrc[8 + e];
      float gf = b2f((unsigned short)gv1[e]);
      float sig = 1.0f / (1.0f + __expf(-gf));
      float val = o * inv * sig;
      unsigned short hb = bfbits(val);
      oh1[e] = hb;
      ol1[e] = bfbits(val - b2f(hb));
    }
    *(ushort8_t*)(gh + idx) = oh0;
    *(ushort8_t*)(gh + idx + 8) = oh1;
    *(ushort8_t*)(gl + idx) = ol0;
    *(ushort8_t*)(gl + idx + 8) = ol1;
  }
}

// ---------------- final GEMM in split-bf16 (hi/lo), 32x64 tiles, fp32 out -------
__global__ __launch_bounds__(256) void gemm_split_kernel(
    const bf16* __restrict__ Ah, const bf16* __restrict__ Al,
    const bf16* __restrict__ Bh, const bf16* __restrict__ Bl,
    const float* __restrict__ bias, float* __restrict__ C) {
  constexpr int K = 512, N = 256;
  __shared__ __align__(16) bf16 Ash[32 * 72];
  __shared__ __align__(16) bf16 Asl[32 * 72];
  __shared__ __align__(16) bf16 Bsh[64 * 72];
  __shared__ __align__(16) bf16 Bsl[64 * 72];
  int n0 = blockIdx.x * 64, m0 = blockIdx.y * 32;
  int t = threadIdx.x, wave = t >> 6, lane = t & 63;
  int lm = lane & 15, quad = lane >> 4, q8 = quad * 8;
  int wm = (wave & 1) * 16, wn = (wave >> 1) * 32;
  f32x4 acc[2] = {};
  for (int k0 = 0; k0 < K; k0 += 64) {
    __syncthreads();
    {
      int r = t >> 3, cg = t & 7;
      size_t ga = (size_t)(m0 + r) * K + k0 + cg * 8;
      *(ushort8_t*)(&Ash[r * 72 + cg * 8]) = *(const ushort8_t*)(Ah + ga);
      *(ushort8_t*)(&Asl[r * 72 + cg * 8]) = *(const ushort8_t*)(Al + ga);
    }
#pragma unroll
    for (int i = 0; i < 2; i++) {
      int id = t + 256 * i, r = id >> 3, cg = id & 7;
      size_t gb = (size_t)(n0 + r) * K + k0 + cg * 8;
      *(ushort8_t*)(&Bsh[r * 72 + cg * 8]) = *(const ushort8_t*)(Bh + gb);
      *(ushort8_t*)(&Bsl[r * 72 + cg * 8]) = *(const ushort8_t*)(Bl + gb);
    }
    __syncthreads();
#pragma unroll
    for (int kk = 0; kk < 64; kk += 32) {
      bf16x8 ah = *(const bf16x8*)(&Ash[(wm + lm) * 72 + kk + q8]);
      bf16x8 al = *(const bf16x8*)(&Asl[(wm + lm) * 72 + kk + q8]);
#pragma unroll
      for (int ni = 0; ni < 2; ni++) {
        bf16x8 bh_ = *(const bf16x8*)(&Bsh[(wn + ni * 16 + lm) * 72 + kk + q8]);
        bf16x8 bl_ = *(const bf16x8*)(&Bsl[(wn + ni * 16 + lm) * 72 + kk + q8]);
        acc[ni] = MFMA32(ah, bh_, acc[ni]);
        acc[ni] = MFMA32(ah, bl_, acc[ni]);
        acc[ni] = MFMA32(al, bh_, acc[ni]);
      }
    }
  }
#pragma unroll
  for (int ni = 0; ni < 2; ni++) {
    int n = n0 + wn + ni * 16 + lm;
    float bvv = bias[n];
    int mb = m0 + wm + quad * 4;
#pragma unroll
    for (int r = 0; r < 4; r++) C[(size_t)(mb + r) * N + n] = acc[ni][r] + bvv;
  }
}

extern "C" void kernel_launch(void* const* d_in, const int* in_sizes, int n_in,
                              void* d_out, int out_size, void* d_ws, size_t ws_size,
                              hipStream_t stream) {
  const float* feat_a = (const float*)d_in[0];
  const float* feat_b = (const float*)d_in[1];
  const void*  mask   = d_in[2];
  const float* Wq = (const float*)d_in[3];
  const float* bq = (const float*)d_in[4];
  const float* Wk = (const float*)d_in[5];
  const float* bk = (const float*)d_in[6];
  const float* Wv = (const float*)d_in[7];
  const float* bv = (const float*)d_in[8];
  const float* Wg = (const float*)d_in[9];
  const float* bg = (const float*)d_in[10];
  const float* Wo = (const float*)d_in[11];
  const float* bo = (const float*)d_in[12];
  const float* law = (const float*)d_in[13];
  const float* lab = (const float*)d_in[14];
  const float* lbw = (const float*)d_in[15];
  const float* lbb = (const float*)d_in[16];
  const float* qlw = (const float*)d_in[17];
  const float* qlb = (const float*)d_in[18];
  const float* klw = (const float*)d_in[19];
  const float* klb = (const float*)d_in[20];

  char* ws = (char*)d_ws;
  size_t off = 0;
  auto alloc = [&](size_t bytes) -> void* {
    void* p = ws + off;
    off += (bytes + 255) & ~(size_t)255;
    return p;
  };
  bf16* fa    = (bf16*)alloc((size_t)MROWS * 256 * 2);
  bf16* fb    = (bf16*)alloc((size_t)MROWS * 256 * 2);
  bf16* Wqt   = (bf16*)alloc((size_t)131072 * 2);
  bf16* Wkt   = (bf16*)alloc((size_t)131072 * 2);
  bf16* Wvt   = (bf16*)alloc((size_t)131072 * 2);
  bf16* Wgt   = (bf16*)alloc((size_t)131072 * 2);
  bf16* Woth  = (bf16*)alloc((size_t)131072 * 2);
  bf16* Wotl  = (bf16*)alloc((size_t)131072 * 2);
  bf16* qb_   = (bf16*)alloc((size_t)MROWS * 512 * 2);
  bf16* kb_   = (bf16*)alloc((size_t)MROWS * 512 * 2);
  bf16* vtb   = (bf16*)alloc((size_t)1024 * 2048 * 2);
  bf16* gbuf  = (bf16*)alloc((size_t)MROWS * 512 * 2);
  bf16* gh    = (bf16*)alloc((size_t)MROWS * 512 * 2);
  bf16* gl    = (bf16*)alloc((size_t)MROWS * 512 * 2);
  u64*  mbits = (u64*)alloc((size_t)131072 * 8);
  float* opart = (float*)alloc((size_t)1024 * 4096 * 4);
  float* lpart = (float*)alloc((size_t)1024 * 64 * 4);
  unsigned* flags = (unsigned*)alloc((size_t)512 * 4);

  prep_kernel<<<6656, 256, 0, stream>>>(
      feat_a, feat_b, law, lab, lbw, lbb, fa, fb,
      Wq, Wk, Wv, Wg, Wo, Wqt, Wkt, Wvt, Wgt, Woth, Wotl, mask, mbits, flags);
  gemm4_kernel<<<dim3(256, 1, 4), 256, 0, stream>>>(
      fa, fb, Wqt, Wkt, Wgt, Wvt, bq, bk, bg, bv,
      qlw, qlb, klw, klb, qb_, kb_, gbuf, vtb);
  attn_kernel<<<dim3(32, 16, 2), 256, 0, stream>>>(
      qb_, kb_, vtb, gbuf, mbits, opart, lpart, flags, gh, gl);
  gemm_split_kernel<<<dim3(4, 128), 256, 0, stream>>>(gh, gl, Woth, Wotl, bo, (float*)d_out);
}

// Round 6
// 196.235 us; speedup vs baseline: 2.0249x; 2.0249x over previous
//
#include <hip/hip_runtime.h>
#include <hip/hip_bf16.h>

using bf16 = __hip_bfloat16;
typedef short bf16x8 __attribute__((ext_vector_type(8)));
typedef float f32x4 __attribute__((ext_vector_type(4)));
typedef unsigned short ushort8_t __attribute__((ext_vector_type(8)));
typedef unsigned uint4_t __attribute__((ext_vector_type(4)));
typedef unsigned long long u64;

static constexpr int NA_ = 2048, NB_ = 2048;
static constexpr int H_ = 8, DH_ = 64, INNER_ = 512;
static constexpr int MROWS = 2 * NA_;  // 4096 rows for both batches

#define MFMA32(a, b, c) __builtin_amdgcn_mfma_f32_16x16x32_bf16(a, b, c, 0, 0, 0)

#if __has_builtin(__builtin_amdgcn_exp2f)
#define EXP2(x) __builtin_amdgcn_exp2f(x)
#else
#define EXP2(x) exp2f(x)
#endif

__device__ __forceinline__ unsigned short bfbits(float x) {
  bf16 h = __float2bfloat16(x);
  return __builtin_bit_cast(unsigned short, h);
}
__device__ __forceinline__ float b2f(unsigned short u) {
  unsigned v = ((unsigned)u) << 16;
  return __builtin_bit_cast(float, v);
}

// pack two fp32 -> dword of 2 bf16 (lo=a, hi=b), round-half-up via +0x8000
__device__ __forceinline__ unsigned pkbf(float a, float b) {
  unsigned ua = __builtin_bit_cast(unsigned, a) + 0x8000u;
  unsigned ub = __builtin_bit_cast(unsigned, b) + 0x8000u;
#if __has_builtin(__builtin_amdgcn_perm)
  // d = [ua.b2, ua.b3, ub.b2, ub.b3]
  return __builtin_amdgcn_perm(ub, ua, 0x07060302u);
#else
  return (ua >> 16) | (ub & 0xFFFF0000u);
#endif
}

// ======== prep: ln_feat (blocks 0..2047) | wconv (2048..4607) | maskpack (4608..6655)
__global__ __launch_bounds__(256) void prep_kernel(
    const float* __restrict__ fa_in, const float* __restrict__ fb_in,
    const float* __restrict__ law, const float* __restrict__ lab,
    const float* __restrict__ lbw, const float* __restrict__ lbb,
    bf16* __restrict__ fa, bf16* __restrict__ fb,
    const float* __restrict__ Wq, const float* __restrict__ Wk,
    const float* __restrict__ Wv, const float* __restrict__ Wg,
    const float* __restrict__ Wo,
    bf16* __restrict__ Wqt, bf16* __restrict__ Wkt,
    bf16* __restrict__ Wvt, bf16* __restrict__ Wgt,
    bf16* __restrict__ Woth, bf16* __restrict__ Wotl,
    const void* __restrict__ maskp, u64* __restrict__ mbits) {
  int blk = blockIdx.x;
  int t = threadIdx.x;
  if (blk < 2048) {
    // ---- LN of feats, one wave per row ----
    int row = blk * 4 + (t >> 6);
    int lane = t & 63;
    const float *src, *w, *bb;
    bf16* dst;
    int r;
    if (row < MROWS) { src = fa_in; w = law; bb = lab; dst = fa; r = row; }
    else             { src = fb_in; w = lbw; bb = lbb; dst = fb; r = row - MROWS; }
    float4 x = *(const float4*)(src + (size_t)r * 256 + lane * 4);
    float s  = (x.x + x.y) + (x.z + x.w);
    float s2 = (x.x * x.x + x.y * x.y) + (x.z * x.z + x.w * x.w);
#pragma unroll
    for (int m = 32; m >= 1; m >>= 1) { s += __shfl_xor(s, m); s2 += __shfl_xor(s2, m); }
    float mean = s * (1.0f / 256.0f);
    float var  = s2 * (1.0f / 256.0f) - mean * mean;
    float rstd = rsqrtf(var + 1e-5f);
    float4 wv = *(const float4*)(w + lane * 4);
    float4 bv = *(const float4*)(bb + lane * 4);
    ushort4 o;
    o.x = bfbits((x.x - mean) * rstd * wv.x + bv.x);
    o.y = bfbits((x.y - mean) * rstd * wv.y + bv.y);
    o.z = bfbits((x.z - mean) * rstd * wv.z + bv.z);
    o.w = bfbits((x.w - mean) * rstd * wv.w + bv.w);
    *(ushort4*)(dst + (size_t)r * 256 + lane * 4) = o;
  } else if (blk < 4608) {
    // ---- weight convert/transpose ----
    int z = (blk - 2048) >> 9;
    int idx = ((blk - 2048) & 511) * 256 + t;  // 0..131071
    if (z < 4) {
      const float* W = (z == 0) ? Wq : (z == 1) ? Wk : (z == 2) ? Wv : Wg;
      bf16* Wt = (z == 0) ? Wqt : (z == 1) ? Wkt : (z == 2) ? Wvt : Wgt;
      int kk = idx >> 9, n = idx & 511;
      Wt[n * 256 + kk] = __float2bfloat16(W[idx]);
    } else {
      int kk = idx >> 8, n = idx & 255;
      float w = Wo[idx];
      bf16 hi = __float2bfloat16(w);
      Woth[n * 512 + kk] = hi;
      Wotl[n * 512 + kk] = __float2bfloat16(w - __bfloat162float(hi));
    }
  } else {
    // ---- mask bit-pack with per-block dtype self-detect ----
    __shared__ unsigned shf[4];
    const unsigned char* mu = (const unsigned char*)maskp;
    bool nz = ((t & 3) != 0) && (mu[t] != 0);
    u64 bal = __ballot(nz);
    if ((t & 63) == 0) shf[t >> 6] = (bal != 0ull) ? 1u : 0u;
    __syncthreads();
    bool m8 = (shf[0] | shf[1] | shf[2] | shf[3]) != 0;  // nonzero off-4 byte => u8
    int lane = t & 63, wid = t >> 6;
    int lb = blk - 4608;
    for (size_t word = (size_t)lb * 4 + wid; word < 131072; word += 8192) {
      size_t e = word * 64 + lane;
      int v = m8 ? (int)mu[e] : ((const int*)maskp)[e];
      u64 b2 = __ballot(v != 0);
      if (lane == 0) mbits[word] = b2;
    }
  }
}

// ======== all four pre-GEMMs in one launch: grid dim3(256,1,4) ========
// z=0: q = LN(fa@Wq+bq) * scale2 (attn scale folded in!)  z=1: k = LN(fb@Wk+bk)
// z=2: g = fa@Wg+bg (bf16 [M][512])  z=3: v^T layout (m-tile 128, n-tile 64)
__global__ __launch_bounds__(256) void gemm4_kernel(
    const bf16* __restrict__ fa, const bf16* __restrict__ fb,
    const bf16* __restrict__ Wqt, const bf16* __restrict__ Wkt,
    const bf16* __restrict__ Wgt, const bf16* __restrict__ Wvt,
    const float* __restrict__ bq, const float* __restrict__ bk,
    const float* __restrict__ bg, const float* __restrict__ bv,
    const float* __restrict__ qlw, const float* __restrict__ qlb,
    const float* __restrict__ klw, const float* __restrict__ klb,
    bf16* __restrict__ qo, bf16* __restrict__ ko,
    bf16* __restrict__ gout, bf16* __restrict__ vout) {
  __shared__ __align__(16) char sm[27648];
  int z = blockIdx.z;
  int t = threadIdx.x, wave = t >> 6, lane = t & 63;
  int lm = lane & 15, quad = lane >> 4, q8 = quad * 8;

  if (z < 2) {
    // ---------- q/k GEMM with fused LayerNorm ----------
    bf16* As = (bf16*)sm;                       // [16][264] = 8448 B
    float* Pred = (float*)(sm + 16896);         // [16][8]
    float* MV   = (float*)(sm + 17408);         // [16][2]
    const bf16* A    = z ? fb : fa;
    const bf16* Wt   = z ? Wkt : Wqt;
    const float* bias = z ? bk : bq;
    const float* lw  = z ? klw : qlw;
    const float* lb  = z ? klb : qlb;
    bf16* out        = z ? ko : qo;
    int m0 = blockIdx.x * 16;
    // stage A 16x256 (stride 264 B-aligned 16)
#pragma unroll
    for (int i = 0; i < 2; i++) {
      int id = t + 256 * i, r = id >> 5, cg = id & 31;
      *(ushort8_t*)(&As[r * 264 + cg * 8]) =
          *(const ushort8_t*)(A + (size_t)(m0 + r) * 256 + cg * 8);
    }
    __syncthreads();
    int n0w = wave * 128;
    f32x4 acc[8] = {};
    const bf16* wrow[8];
#pragma unroll
    for (int ni = 0; ni < 8; ni++) wrow[ni] = Wt + (size_t)(n0w + ni * 16 + lm) * 256;
#pragma unroll
    for (int ks = 0; ks < 8; ks++) {
      int k0 = ks * 32;
      bf16x8 af = *(const bf16x8*)(&As[lm * 264 + k0 + q8]);
#pragma unroll
      for (int ni = 0; ni < 8; ni++) {
        bf16x8 bf_ = *(const bf16x8*)(wrow[ni] + k0 + q8);
        acc[ni] = MFMA32(af, bf_, acc[ni]);
      }
    }
    float bvv[8];
#pragma unroll
    for (int ni = 0; ni < 8; ni++) bvv[ni] = bias[n0w + ni * 16 + lm];
#pragma unroll
    for (int ni = 0; ni < 8; ni++)
#pragma unroll
      for (int r = 0; r < 4; r++) acc[ni][r] += bvv[ni];
    // per-row stats over the wave's 128 cols
#pragma unroll
    for (int r = 0; r < 4; r++) {
      float s = 0.f, s2 = 0.f;
#pragma unroll
      for (int ni = 0; ni < 8; ni++) { s += acc[ni][r]; s2 += acc[ni][r] * acc[ni][r]; }
#pragma unroll
      for (int m = 1; m <= 8; m <<= 1) { s += __shfl_xor(s, m); s2 += __shfl_xor(s2, m); }
      if (lm == 0) {
        int row = quad * 4 + r;
        Pred[row * 8 + wave * 2]     = s;
        Pred[row * 8 + wave * 2 + 1] = s2;
      }
    }
    __syncthreads();
    if (t < 16) {
      float s = 0.f, s2 = 0.f;
#pragma unroll
      for (int w = 0; w < 4; w++) { s += Pred[t * 8 + w * 2]; s2 += Pred[t * 8 + w * 2 + 1]; }
      float mean = s * (1.0f / 512.0f);
      float var  = s2 * (1.0f / 512.0f) - mean * mean;
      MV[t * 2]     = mean;
      MV[t * 2 + 1] = rsqrtf(var + 1e-5f);
    }
    __syncthreads();
    float lww[8], lbb_[8];
#pragma unroll
    for (int ni = 0; ni < 8; ni++) {
      lww[ni]  = lw[n0w + ni * 16 + lm];
      lbb_[ni] = lb[n0w + ni * 16 + lm];
    }
    if (z == 0) {
      // fold attn scale (1/sqrt(dh) * log2(e)) into q so attn does p=exp2(s) raw
      const float SC = 0.125f * 1.44269504088896f;
#pragma unroll
      for (int ni = 0; ni < 8; ni++) { lww[ni] *= SC; lbb_[ni] *= SC; }
    }
#pragma unroll
    for (int r = 0; r < 4; r++) {
      int row = quad * 4 + r;
      float mean = MV[row * 2], rstd = MV[row * 2 + 1];
      size_t obase = (size_t)(m0 + row) * 512 + n0w;
#pragma unroll
      for (int ni = 0; ni < 8; ni++)
        out[obase + ni * 16 + lm] =
            __float2bfloat16((acc[ni][r] - mean) * rstd * lww[ni] + lbb_[ni]);
    }
  } else {
    // ---------- g/v GEMM: m-tile 128, n-tile 64 (stride 72, 16-B aligned) ----------
    bf16* As = (bf16*)sm;                 // [128][72] = 18432 B
    bf16* Bs = (bf16*)(sm + 18432);       // [64][72]  = 9216 B
    const bf16* A    = (z == 3) ? fb : fa;
    const bf16* Wt   = (z == 3) ? Wvt : Wgt;
    const float* bias = (z == 3) ? bv : bg;
    int x = blockIdx.x;
    int m0 = (x >> 3) * 128, n0 = (x & 7) * 64;
    int wm = wave * 32;
    f32x4 acc[2][4] = {};
    for (int k0 = 0; k0 < 256; k0 += 64) {
      __syncthreads();
#pragma unroll
      for (int i = 0; i < 4; i++) {
        int id = t + 256 * i, r = id >> 3, cg = id & 7;
        *(ushort8_t*)(&As[r * 72 + cg * 8]) =
            *(const ushort8_t*)(A + (size_t)(m0 + r) * 256 + k0 + cg * 8);
      }
#pragma unroll
      for (int i = 0; i < 2; i++) {
        int id = t + 256 * i, r = id >> 3, cg = id & 7;
        *(ushort8_t*)(&Bs[r * 72 + cg * 8]) =
            *(const ushort8_t*)(Wt + (size_t)(n0 + r) * 256 + k0 + cg * 8);
      }
      __syncthreads();
#pragma unroll
      for (int kk = 0; kk < 64; kk += 32) {
        bf16x8 af[2], bf_[4];
#pragma unroll
        for (int mi = 0; mi < 2; mi++)
          af[mi] = *(const bf16x8*)(&As[(wm + mi * 16 + lm) * 72 + kk + q8]);
#pragma unroll
        for (int ni = 0; ni < 4; ni++)
          bf_[ni] = *(const bf16x8*)(&Bs[(ni * 16 + lm) * 72 + kk + q8]);
#pragma unroll
        for (int mi = 0; mi < 2; mi++)
#pragma unroll
          for (int ni = 0; ni < 4; ni++)
            acc[mi][ni] = MFMA32(af[mi], bf_[ni], acc[mi][ni]);
      }
    }
    if (z == 2) {
#pragma unroll
      for (int mi = 0; mi < 2; mi++)
#pragma unroll
        for (int ni = 0; ni < 4; ni++) {
          int nn = n0 + ni * 16 + lm;
          float bvv = bias[nn];
          int mb = m0 + wm + mi * 16 + quad * 4;
#pragma unroll
          for (int r = 0; r < 4; r++)
            gout[(size_t)(mb + r) * 512 + nn] = __float2bfloat16(acc[mi][ni][r] + bvv);
        }
    } else {
      // v^T: bounce through LDS [64 d][136] for coalesced [d][j] write
      __syncthreads();
      bf16* buf = (bf16*)sm;
#pragma unroll
      for (int mi = 0; mi < 2; mi++)
#pragma unroll
        for (int ni = 0; ni < 4; ni++) {
          int d_local = ni * 16 + lm;
          float bvv = bias[n0 + d_local];
          int j_local = wm + mi * 16 + quad * 4;
#pragma unroll
          for (int r = 0; r < 4; r++)
            buf[d_local * 136 + j_local + r] = __float2bfloat16(acc[mi][ni][r] + bvv);
        }
      __syncthreads();
      int bidx2 = m0 >> 11, j0g = m0 & 2047, hh = n0 >> 6;
      int dl = t >> 2, jseg = (t & 3) * 32;
      bf16* dstrow = vout + (size_t)((bidx2 * 8 + hh) * 64 + dl) * 2048 + j0g + jseg;
#pragma unroll
      for (int c = 0; c < 4; c++)
        *(ushort8_t*)(dstrow + c * 8) = *(const ushort8_t*)(&buf[dl * 136 + jseg + c * 8]);
    }
  }
}

// ---------------- flash attention: 2-tile/iter, 32-i waves, in-block merge -------
// 512 thr, 8 waves = (jh: which of the 2 staged 64-j tiles, wj: 32-j slice,
// wi: 32-i rows). 16 iters x 128 j. Q in registers from global. LDS = double
// buffer of [K0|V0|K1|V1] (73728 B) + Lbuf -> 2 blocks/CU, 16 waves/CU; LDS
// b128 per block HALVED vs one-tile (1024) and barriers halved (16).
// K sigma-permuted per 32-row group -> QK^T C-regs pack into k32 PV A-frag
// (P register-only). l on matrix pipe via ones-column frag.
// Epilogue: in-block 4-way serialized Om merge + distributed 512-thr write.
// NO cross-block fences/atomics (R5 lesson: device fences flush L2, ~7x cost).
__global__ __launch_bounds__(512, 4) void attn_kernel(
    const bf16* __restrict__ q, const bf16* __restrict__ k,
    const bf16* __restrict__ vt, const bf16* __restrict__ g,
    const u64* __restrict__ mbits,
    bf16* __restrict__ gh, bf16* __restrict__ gl) {
  __shared__ __align__(16) char smem[74752];
  bf16* KVB = (bf16*)smem;               // 2 bufs x [K0|V0|K1|V1], 4608 elems each
  float* Om = (float*)smem;              // epilogue overlay: 64*66*4 = 16896 B
  float* Lbuf = (float*)(smem + 73728);  // 4 groups x 64 = 1024 B
  constexpr int TILE = 64 * 72;          // elems per staged matrix
  constexpr int BUFE = 4 * TILE;         // elems per dbuf slot

  // XCD-locality swizzle (proven in R4): each XCD owns 2 whole bh
  int flat = blockIdx.y * 32 + blockIdx.x;
  int bh = (flat & 7) * 2 + (flat >> 8);
  int qt = (flat >> 3) & 31;
  int bidx = bh >> 3, h = bh & 7;
  int i0 = qt * 64;
  int t = threadIdx.x, wave = t >> 6, lane = t & 63;
  int wi = wave & 1, wj = (wave >> 1) & 1, jh = wave >> 2;
  int lm = lane & 15, quad = lane >> 4, q8 = quad * 8;
  int wj32 = wj * 32, wi32 = wi * 32;
  int srow = t >> 3, scg = (t & 7) * 8;  // staging: row 0..63, col-chunk 0..7

  // sigma-permuted K staging row (within each 32-row group)
  int sg = srow & 31;
  int ksrow = (srow & 32) + (((sg & 4) << 2) | ((sg & 24) >> 1) | (sg & 3));
  int ksl = ksrow * 72 + scg;
  int vsl = srow * 72 + scg;

  const bf16* kb = k + (size_t)(bidx * NB_) * INNER_ + h * DH_;
  const bf16* vb = vt + (size_t)(bh * DH_) * NB_;
  const bf16* ksrc = kb + (size_t)srow * INNER_ + scg;   // + T*64*INNER_
  const bf16* vsrc = vb + (size_t)srow * NB_ + scg;      // + T*64

  // Q fragments directly from global (one-time)
  const bf16* qbase = q + (size_t)(bidx * NA_ + i0 + wi32 + lm) * INNER_ + h * DH_;
  bf16x8 bq00 = *(const bf16x8*)(qbase + q8);
  bf16x8 bq01 = *(const bf16x8*)(qbase + 32 + q8);
  bf16x8 bq10 = *(const bf16x8*)(qbase + 16 * INNER_ + q8);
  bf16x8 bq11 = *(const bf16x8*)(qbase + 16 * INNER_ + 32 + q8);

  // constant B fragment: ones-column at n=0 (bf16 1.0 = 0x3F80)
  bf16x8 bone;
  {
    short onev = (lm == 0) ? (short)0x3F80 : (short)0;
#pragma unroll
    for (int i = 0; i < 8; i++) bone[i] = onev;
  }

  f32x4 oacc[2][4] = {};
  f32x4 lacc[2] = {};

  const u64* mrp0 = mbits + (size_t)(bidx * NA_ + i0 + wi32 + lm) * (NB_ / 64);
  const u64* mrp1 = mrp0 + (size_t)16 * (NB_ / 64);
  int shp = wj32 + quad * 8;

  // prologue: stage tiles 0,1 into buf0; prefetch tiles 2,3 into regs
  ushort8_t kra = *(const ushort8_t*)(ksrc);
  ushort8_t krb = *(const ushort8_t*)(ksrc + (size_t)64 * INNER_);
  ushort8_t vra = *(const ushort8_t*)(vsrc);
  ushort8_t vrb = *(const ushort8_t*)(vsrc + 64);
  *(ushort8_t*)(&KVB[ksl]) = kra;
  *(ushort8_t*)(&KVB[TILE + vsl]) = vra;
  *(ushort8_t*)(&KVB[2 * TILE + ksl]) = krb;
  *(ushort8_t*)(&KVB[3 * TILE + vsl]) = vrb;
  kra = *(const ushort8_t*)(ksrc + (size_t)128 * INNER_);
  krb = *(const ushort8_t*)(ksrc + (size_t)192 * INNER_);
  vra = *(const ushort8_t*)(vsrc + 128);
  vrb = *(const ushort8_t*)(vsrc + 192);
  u64 smw0 = mrp0[jh] >> shp;
  u64 smw1 = mrp1[jh] >> shp;
  __syncthreads();  // buf0 ready

  for (int it = 0; it < 16; it++) {
    bf16* buf = KVB + (it & 1) * BUFE;
    bf16* Ks = buf + jh * (2 * TILE);
    bf16* Vs = Ks + TILE;
    // write next tile-pair into alt buffer (off critical path)
    if (it < 15) {
      bf16* nb = KVB + ((it + 1) & 1) * BUFE;
      *(ushort8_t*)(&nb[ksl]) = kra;
      *(ushort8_t*)(&nb[TILE + vsl]) = vra;
      *(ushort8_t*)(&nb[2 * TILE + ksl]) = krb;
      *(ushort8_t*)(&nb[3 * TILE + vsl]) = vrb;
    }
    // issue global loads 2 iterations (4 tiles) ahead
    if (it < 14) {
      int T = (it + 2) * 2;
      kra = *(const ushort8_t*)(ksrc + (size_t)T * (64 * INNER_));
      krb = *(const ushort8_t*)(ksrc + (size_t)(T + 1) * (64 * INNER_));
      vra = *(const ushort8_t*)(vsrc + T * 64);
      vrb = *(const ushort8_t*)(vsrc + (T + 1) * 64);
    }
    u64 nm0 = smw0, nm1 = smw1;
    if (it < 15) {
      nm0 = mrp0[(it + 1) * 2 + jh] >> shp;
      nm1 = mrp1[(it + 1) * 2 + jh] >> shp;
    }

    // QK^T: wave's 32-j slice (sigma-permuted rows) x 32 i
    bf16x8 a00 = *(const bf16x8*)(&Ks[(wj32 + lm) * 72 + q8]);
    bf16x8 a01 = *(const bf16x8*)(&Ks[(wj32 + lm) * 72 + 32 + q8]);
    bf16x8 a10 = *(const bf16x8*)(&Ks[(wj32 + 16 + lm) * 72 + q8]);
    bf16x8 a11 = *(const bf16x8*)(&Ks[(wj32 + 16 + lm) * 72 + 32 + q8]);
    f32x4 st00 = {0.f, 0.f, 0.f, 0.f}, st01 = {0.f, 0.f, 0.f, 0.f};
    f32x4 st10 = {0.f, 0.f, 0.f, 0.f}, st11 = {0.f, 0.f, 0.f, 0.f};
    st00 = MFMA32(a00, bq00, st00); st00 = MFMA32(a01, bq01, st00);
    st01 = MFMA32(a10, bq00, st01); st01 = MFMA32(a11, bq01, st01);
    st10 = MFMA32(a00, bq10, st10); st10 = MFMA32(a01, bq11, st10);
    st11 = MFMA32(a10, bq10, st11); st11 = MFMA32(a11, bq11, st11);

    // p = exp2(masked s); lane's j = wj32 + quad*8 + js*4 + r -> bit js*4+r
    float p00[4], p01[4], p10[4], p11[4];
#pragma unroll
    for (int r = 0; r < 4; r++) {
      p00[r] = EXP2(((smw0 >> r) & 1ull) ? st00[r] : -200.0f);
      p01[r] = EXP2(((smw0 >> (4 + r)) & 1ull) ? st01[r] : -200.0f);
      p10[r] = EXP2(((smw1 >> r) & 1ull) ? st10[r] : -200.0f);
      p11[r] = EXP2(((smw1 >> (4 + r)) & 1ull) ? st11[r] : -200.0f);
    }

    // pack into k32 PV A-fragments (P register-only)
    uint4_t u0, u1;
    u0[0] = pkbf(p00[0], p00[1]);
    u0[1] = pkbf(p00[2], p00[3]);
    u0[2] = pkbf(p01[0], p01[1]);
    u0[3] = pkbf(p01[2], p01[3]);
    u1[0] = pkbf(p10[0], p10[1]);
    u1[1] = pkbf(p10[2], p10[3]);
    u1[2] = pkbf(p11[0], p11[1]);
    u1[3] = pkbf(p11[2], p11[3]);
    bf16x8 pa0 = __builtin_bit_cast(bf16x8, u0);
    bf16x8 pa1 = __builtin_bit_cast(bf16x8, u1);

    // PV: A = P [m=i][k=j32], B = V^T [n=d][k=j] -> O[i][d]
#pragma unroll
    for (int c = 0; c < 4; c++) {
      bf16x8 v_ = *(const bf16x8*)(&Vs[(c * 16 + lm) * 72 + wj32 + q8]);
      oacc[0][c] = MFMA32(pa0, v_, oacc[0][c]);
      oacc[1][c] = MFMA32(pa1, v_, oacc[1][c]);
    }
    lacc[0] = MFMA32(pa0, bone, lacc[0]);
    lacc[1] = MFMA32(pa1, bone, lacc[1]);

    smw0 = nm0;
    smw1 = nm1;
    __syncthreads();  // alt-buffer writes visible; current reads done
  }

  // -------- epilogue: in-block 4-way merge + distributed write --------
  int grp = jh * 2 + wj;
  if (lm == 0) {
#pragma unroll
    for (int is_ = 0; is_ < 2; is_++)
#pragma unroll
      for (int r = 0; r < 4; r++)
        Lbuf[grp * 64 + wi32 + is_ * 16 + quad * 4 + r] = lacc[is_][r];
  }
  if (grp == 3) {
#pragma unroll
    for (int is_ = 0; is_ < 2; is_++)
#pragma unroll
      for (int c = 0; c < 4; c++)
#pragma unroll
        for (int r = 0; r < 4; r++)
          Om[(wi32 + is_ * 16 + quad * 4 + r) * 66 + c * 16 + lm] = oacc[is_][c][r];
  }
  __syncthreads();
  if (grp == 2) {
#pragma unroll
    for (int is_ = 0; is_ < 2; is_++)
#pragma unroll
      for (int c = 0; c < 4; c++)
#pragma unroll
        for (int r = 0; r < 4; r++)
          Om[(wi32 + is_ * 16 + quad * 4 + r) * 66 + c * 16 + lm] += oacc[is_][c][r];
  }
  __syncthreads();
  if (grp == 1) {
#pragma unroll
    for (int is_ = 0; is_ < 2; is_++)
#pragma unroll
      for (int c = 0; c < 4; c++)
#pragma unroll
        for (int r = 0; r < 4; r++)
          Om[(wi32 + is_ * 16 + quad * 4 + r) * 66 + c * 16 + lm] += oacc[is_][c][r];
  }
  __syncthreads();
  if (grp == 0) {
#pragma unroll
    for (int is_ = 0; is_ < 2; is_++)
#pragma unroll
      for (int c = 0; c < 4; c++)
#pragma unroll
        for (int r = 0; r < 4; r++)
          Om[(wi32 + is_ * 16 + quad * 4 + r) * 66 + c * 16 + lm] += oacc[is_][c][r];
  }
  __syncthreads();
  // distributed final write: thread -> row t>>3, cols (t&7)*8 .. +7
  {
    int row = t >> 3;
    int col = (t & 7) * 8;
    float l = Lbuf[row] + Lbuf[64 + row] + Lbuf[128 + row] + Lbuf[192 + row];
    float inv = 1.0f / l;
    size_t idx = (size_t)(bidx * NA_ + i0 + row) * INNER_ + h * DH_ + col;
    ushort8_t gv = *(const ushort8_t*)(g + idx);
    ushort8_t oh, ol;
#pragma unroll
    for (int e = 0; e < 8; e++) {
      float o = Om[row * 66 + col + e];
      float gf = b2f((unsigned short)gv[e]);
      float sig = 1.0f / (1.0f + __expf(-gf));
      float val = o * inv * sig;
      unsigned short hb = bfbits(val);
      oh[e] = hb;
      ol[e] = bfbits(val - b2f(hb));
    }
    *(ushort8_t*)(gh + idx) = oh;
    *(ushort8_t*)(gl + idx) = ol;
  }
}

// ---------------- final GEMM in split-bf16 (hi/lo), 32x64 tiles, fp32 out -------
__global__ __launch_bounds__(256) void gemm_split_kernel(
    const bf16* __restrict__ Ah, const bf16* __restrict__ Al,
    const bf16* __restrict__ Bh, const bf16* __restrict__ Bl,
    const float* __restrict__ bias, float* __restrict__ C) {
  constexpr int K = 512, N = 256;
  __shared__ __align__(16) bf16 Ash[32 * 72];
  __shared__ __align__(16) bf16 Asl[32 * 72];
  __shared__ __align__(16) bf16 Bsh[64 * 72];
  __shared__ __align__(16) bf16 Bsl[64 * 72];
  int n0 = blockIdx.x * 64, m0 = blockIdx.y * 32;
  int t = threadIdx.x, wave = t >> 6, lane = t & 63;
  int lm = lane & 15, quad = lane >> 4, q8 = quad * 8;
  int wm = (wave & 1) * 16, wn = (wave >> 1) * 32;
  f32x4 acc[2] = {};
  for (int k0 = 0; k0 < K; k0 += 64) {
    __syncthreads();
    {
      int r = t >> 3, cg = t & 7;
      size_t ga = (size_t)(m0 + r) * K + k0 + cg * 8;
      *(ushort8_t*)(&Ash[r * 72 + cg * 8]) = *(const ushort8_t*)(Ah + ga);
      *(ushort8_t*)(&Asl[r * 72 + cg * 8]) = *(const ushort8_t*)(Al + ga);
    }
#pragma unroll
    for (int i = 0; i < 2; i++) {
      int id = t + 256 * i, r = id >> 3, cg = id & 7;
      size_t gb = (size_t)(n0 + r) * K + k0 + cg * 8;
      *(ushort8_t*)(&Bsh[r * 72 + cg * 8]) = *(const ushort8_t*)(Bh + gb);
      *(ushort8_t*)(&Bsl[r * 72 + cg * 8]) = *(const ushort8_t*)(Bl + gb);
    }
    __syncthreads();
#pragma unroll
    for (int kk = 0; kk < 64; kk += 32) {
      bf16x8 ah = *(const bf16x8*)(&Ash[(wm + lm) * 72 + kk + q8]);
      bf16x8 al = *(const bf16x8*)(&Asl[(wm + lm) * 72 + kk + q8]);
#pragma unroll
      for (int ni = 0; ni < 2; ni++) {
        bf16x8 bh_ = *(const bf16x8*)(&Bsh[(wn + ni * 16 + lm) * 72 + kk + q8]);
        bf16x8 bl_ = *(const bf16x8*)(&Bsl[(wn + ni * 16 + lm) * 72 + kk + q8]);
        acc[ni] = MFMA32(ah, bh_, acc[ni]);
        acc[ni] = MFMA32(ah, bl_, acc[ni]);
        acc[ni] = MFMA32(al, bh_, acc[ni]);
      }
    }
  }
#pragma unroll
  for (int ni = 0; ni < 2; ni++) {
    int n = n0 + wn + ni * 16 + lm;
    float bvv = bias[n];
    int mb = m0 + wm + quad * 4;
#pragma unroll
    for (int r = 0; r < 4; r++) C[(size_t)(mb + r) * N + n] = acc[ni][r] + bvv;
  }
}

extern "C" void kernel_launch(void* const* d_in, const int* in_sizes, int n_in,
                              void* d_out, int out_size, void* d_ws, size_t ws_size,
                              hipStream_t stream) {
  const float* feat_a = (const float*)d_in[0];
  const float* feat_b = (const float*)d_in[1];
  const void*  mask   = d_in[2];
  const float* Wq = (const float*)d_in[3];
  const float* bq = (const float*)d_in[4];
  const float* Wk = (const float*)d_in[5];
  const float* bk = (const float*)d_in[6];
  const float* Wv = (const float*)d_in[7];
  const float* bv = (const float*)d_in[8];
  const float* Wg = (const float*)d_in[9];
  const float* bg = (const float*)d_in[10];
  const float* Wo = (const float*)d_in[11];
  const float* bo = (const float*)d_in[12];
  const float* law = (const float*)d_in[13];
  const float* lab = (const float*)d_in[14];
  const float* lbw = (const float*)d_in[15];
  const float* lbb = (const float*)d_in[16];
  const float* qlw = (const float*)d_in[17];
  const float* qlb = (const float*)d_in[18];
  const float* klw = (const float*)d_in[19];
  const float* klb = (const float*)d_in[20];

  char* ws = (char*)d_ws;
  size_t off = 0;
  auto alloc = [&](size_t bytes) -> void* {
    void* p = ws + off;
    off += (bytes + 255) & ~(size_t)255;
    return p;
  };
  bf16* fa    = (bf16*)alloc((size_t)MROWS * 256 * 2);
  bf16* fb    = (bf16*)alloc((size_t)MROWS * 256 * 2);
  bf16* Wqt   = (bf16*)alloc((size_t)131072 * 2);
  bf16* Wkt   = (bf16*)alloc((size_t)131072 * 2);
  bf16* Wvt   = (bf16*)alloc((size_t)131072 * 2);
  bf16* Wgt   = (bf16*)alloc((size_t)131072 * 2);
  bf16* Woth  = (bf16*)alloc((size_t)131072 * 2);
  bf16* Wotl  = (bf16*)alloc((size_t)131072 * 2);
  bf16* qb_   = (bf16*)alloc((size_t)MROWS * 512 * 2);
  bf16* kb_   = (bf16*)alloc((size_t)MROWS * 512 * 2);
  bf16* vtb   = (bf16*)alloc((size_t)1024 * 2048 * 2);
  bf16* gbuf  = (bf16*)alloc((size_t)MROWS * 512 * 2);
  bf16* gh    = (bf16*)alloc((size_t)MROWS * 512 * 2);
  bf16* gl    = (bf16*)alloc((size_t)MROWS * 512 * 2);
  u64*  mbits = (u64*)alloc((size_t)131072 * 8);

  prep_kernel<<<6656, 256, 0, stream>>>(
      feat_a, feat_b, law, lab, lbw, lbb, fa, fb,
      Wq, Wk, Wv, Wg, Wo, Wqt, Wkt, Wvt, Wgt, Woth, Wotl, mask, mbits);
  gemm4_kernel<<<dim3(256, 1, 4), 256, 0, stream>>>(
      fa, fb, Wqt, Wkt, Wgt, Wvt, bq, bk, bg, bv,
      qlw, qlb, klw, klb, qb_, kb_, gbuf, vtb);
  attn_kernel<<<dim3(32, 16), 512, 0, stream>>>(qb_, kb_, vtb, gbuf, mbits, gh, gl);
  gemm_split_kernel<<<dim3(4, 128), 256, 0, stream>>>(gh, gl, Woth, Wotl, bo, (float*)d_out);
}

// Round 7
// 191.570 us; speedup vs baseline: 2.0742x; 1.0244x over previous
//
#include <hip/hip_runtime.h>
#include <hip/hip_bf16.h>

using bf16 = __hip_bfloat16;
typedef short bf16x8 __attribute__((ext_vector_type(8)));
typedef float f32x4 __attribute__((ext_vector_type(4)));
typedef unsigned short ushort8_t __attribute__((ext_vector_type(8)));
typedef unsigned uint4_t __attribute__((ext_vector_type(4)));
typedef unsigned long long u64;

static constexpr int NA_ = 2048, NB_ = 2048;
static constexpr int H_ = 8, DH_ = 64, INNER_ = 512;
static constexpr int MROWS = 2 * NA_;  // 4096 rows for both batches

#define MFMA32(a, b, c) __builtin_amdgcn_mfma_f32_16x16x32_bf16(a, b, c, 0, 0, 0)

#if __has_builtin(__builtin_amdgcn_exp2f)
#define EXP2(x) __builtin_amdgcn_exp2f(x)
#else
#define EXP2(x) exp2f(x)
#endif

__device__ __forceinline__ unsigned short bfbits(float x) {
  bf16 h = __float2bfloat16(x);
  return __builtin_bit_cast(unsigned short, h);
}
__device__ __forceinline__ float b2f(unsigned short u) {
  unsigned v = ((unsigned)u) << 16;
  return __builtin_bit_cast(float, v);
}

// pack two fp32 -> dword of 2 bf16 (lo=a, hi=b), round-half-up via +0x8000
__device__ __forceinline__ unsigned pkbf(float a, float b) {
  unsigned ua = __builtin_bit_cast(unsigned, a) + 0x8000u;
  unsigned ub = __builtin_bit_cast(unsigned, b) + 0x8000u;
#if __has_builtin(__builtin_amdgcn_perm)
  // d = [ua.b2, ua.b3, ub.b2, ub.b3]
  return __builtin_amdgcn_perm(ub, ua, 0x07060302u);
#else
  return (ua >> 16) | (ub & 0xFFFF0000u);
#endif
}

// ======== prep: ln_feat (blocks 0..2047) | wconv (2048..4607) | maskpack (4608..6655)
__global__ __launch_bounds__(256) void prep_kernel(
    const float* __restrict__ fa_in, const float* __restrict__ fb_in,
    const float* __restrict__ law, const float* __restrict__ lab,
    const float* __restrict__ lbw, const float* __restrict__ lbb,
    bf16* __restrict__ fa, bf16* __restrict__ fb,
    const float* __restrict__ Wq, const float* __restrict__ Wk,
    const float* __restrict__ Wv, const float* __restrict__ Wg,
    const float* __restrict__ Wo,
    bf16* __restrict__ Wqt, bf16* __restrict__ Wkt,
    bf16* __restrict__ Wvt, bf16* __restrict__ Wgt,
    bf16* __restrict__ Woth, bf16* __restrict__ Wotl,
    const void* __restrict__ maskp, u64* __restrict__ mbits) {
  int blk = blockIdx.x;
  int t = threadIdx.x;
  if (blk < 2048) {
    // ---- LN of feats, one wave per row ----
    int row = blk * 4 + (t >> 6);
    int lane = t & 63;
    const float *src, *w, *bb;
    bf16* dst;
    int r;
    if (row < MROWS) { src = fa_in; w = law; bb = lab; dst = fa; r = row; }
    else             { src = fb_in; w = lbw; bb = lbb; dst = fb; r = row - MROWS; }
    float4 x = *(const float4*)(src + (size_t)r * 256 + lane * 4);
    float s  = (x.x + x.y) + (x.z + x.w);
    float s2 = (x.x * x.x + x.y * x.y) + (x.z * x.z + x.w * x.w);
#pragma unroll
    for (int m = 32; m >= 1; m >>= 1) { s += __shfl_xor(s, m); s2 += __shfl_xor(s2, m); }
    float mean = s * (1.0f / 256.0f);
    float var  = s2 * (1.0f / 256.0f) - mean * mean;
    float rstd = rsqrtf(var + 1e-5f);
    float4 wv = *(const float4*)(w + lane * 4);
    float4 bv = *(const float4*)(bb + lane * 4);
    ushort4 o;
    o.x = bfbits((x.x - mean) * rstd * wv.x + bv.x);
    o.y = bfbits((x.y - mean) * rstd * wv.y + bv.y);
    o.z = bfbits((x.z - mean) * rstd * wv.z + bv.z);
    o.w = bfbits((x.w - mean) * rstd * wv.w + bv.w);
    *(ushort4*)(dst + (size_t)r * 256 + lane * 4) = o;
  } else if (blk < 4608) {
    // ---- weight convert/transpose ----
    int z = (blk - 2048) >> 9;
    int idx = ((blk - 2048) & 511) * 256 + t;  // 0..131071
    if (z < 4) {
      const float* W = (z == 0) ? Wq : (z == 1) ? Wk : (z == 2) ? Wv : Wg;
      bf16* Wt = (z == 0) ? Wqt : (z == 1) ? Wkt : (z == 2) ? Wvt : Wgt;
      int kk = idx >> 9, n = idx & 511;
      Wt[n * 256 + kk] = __float2bfloat16(W[idx]);
    } else {
      int kk = idx >> 8, n = idx & 255;
      float w = Wo[idx];
      bf16 hi = __float2bfloat16(w);
      Woth[n * 512 + kk] = hi;
      Wotl[n * 512 + kk] = __float2bfloat16(w - __bfloat162float(hi));
    }
  } else {
    // ---- mask bit-pack with per-block dtype self-detect ----
    __shared__ unsigned shf[4];
    const unsigned char* mu = (const unsigned char*)maskp;
    bool nz = ((t & 3) != 0) && (mu[t] != 0);
    u64 bal = __ballot(nz);
    if ((t & 63) == 0) shf[t >> 6] = (bal != 0ull) ? 1u : 0u;
    __syncthreads();
    bool m8 = (shf[0] | shf[1] | shf[2] | shf[3]) != 0;  // nonzero off-4 byte => u8
    int lane = t & 63, wid = t >> 6;
    int lb = blk - 4608;
    for (size_t word = (size_t)lb * 4 + wid; word < 131072; word += 8192) {
      size_t e = word * 64 + lane;
      int v = m8 ? (int)mu[e] : ((const int*)maskp)[e];
      u64 b2 = __ballot(v != 0);
      if (lane == 0) mbits[word] = b2;
    }
  }
}

// ======== all four pre-GEMMs in one launch: grid dim3(256,1,4) ========
// z=0: q = LN(fa@Wq+bq) * scale2 (attn scale folded in!)  z=1: k = LN(fb@Wk+bk)
// z=2: g = fa@Wg+bg (bf16 [M][512])  z=3: v^T layout (m-tile 128, n-tile 64)
__global__ __launch_bounds__(256) void gemm4_kernel(
    const bf16* __restrict__ fa, const bf16* __restrict__ fb,
    const bf16* __restrict__ Wqt, const bf16* __restrict__ Wkt,
    const bf16* __restrict__ Wgt, const bf16* __restrict__ Wvt,
    const float* __restrict__ bq, const float* __restrict__ bk,
    const float* __restrict__ bg, const float* __restrict__ bv,
    const float* __restrict__ qlw, const float* __restrict__ qlb,
    const float* __restrict__ klw, const float* __restrict__ klb,
    bf16* __restrict__ qo, bf16* __restrict__ ko,
    bf16* __restrict__ gout, bf16* __restrict__ vout) {
  __shared__ __align__(16) char sm[27648];
  int z = blockIdx.z;
  int t = threadIdx.x, wave = t >> 6, lane = t & 63;
  int lm = lane & 15, quad = lane >> 4, q8 = quad * 8;

  if (z < 2) {
    // ---------- q/k GEMM with fused LayerNorm ----------
    bf16* As = (bf16*)sm;                       // [16][264] = 8448 B
    float* Pred = (float*)(sm + 16896);         // [16][8]
    float* MV   = (float*)(sm + 17408);         // [16][2]
    const bf16* A    = z ? fb : fa;
    const bf16* Wt   = z ? Wkt : Wqt;
    const float* bias = z ? bk : bq;
    const float* lw  = z ? klw : qlw;
    const float* lb  = z ? klb : qlb;
    bf16* out        = z ? ko : qo;
    int m0 = blockIdx.x * 16;
    // stage A 16x256 (stride 264 B-aligned 16)
#pragma unroll
    for (int i = 0; i < 2; i++) {
      int id = t + 256 * i, r = id >> 5, cg = id & 31;
      *(ushort8_t*)(&As[r * 264 + cg * 8]) =
          *(const ushort8_t*)(A + (size_t)(m0 + r) * 256 + cg * 8);
    }
    __syncthreads();
    int n0w = wave * 128;
    f32x4 acc[8] = {};
    const bf16* wrow[8];
#pragma unroll
    for (int ni = 0; ni < 8; ni++) wrow[ni] = Wt + (size_t)(n0w + ni * 16 + lm) * 256;
#pragma unroll
    for (int ks = 0; ks < 8; ks++) {
      int k0 = ks * 32;
      bf16x8 af = *(const bf16x8*)(&As[lm * 264 + k0 + q8]);
#pragma unroll
      for (int ni = 0; ni < 8; ni++) {
        bf16x8 bf_ = *(const bf16x8*)(wrow[ni] + k0 + q8);
        acc[ni] = MFMA32(af, bf_, acc[ni]);
      }
    }
    float bvv[8];
#pragma unroll
    for (int ni = 0; ni < 8; ni++) bvv[ni] = bias[n0w + ni * 16 + lm];
#pragma unroll
    for (int ni = 0; ni < 8; ni++)
#pragma unroll
      for (int r = 0; r < 4; r++) acc[ni][r] += bvv[ni];
    // per-row stats over the wave's 128 cols
#pragma unroll
    for (int r = 0; r < 4; r++) {
      float s = 0.f, s2 = 0.f;
#pragma unroll
      for (int ni = 0; ni < 8; ni++) { s += acc[ni][r]; s2 += acc[ni][r] * acc[ni][r]; }
#pragma unroll
      for (int m = 1; m <= 8; m <<= 1) { s += __shfl_xor(s, m); s2 += __shfl_xor(s2, m); }
      if (lm == 0) {
        int row = quad * 4 + r;
        Pred[row * 8 + wave * 2]     = s;
        Pred[row * 8 + wave * 2 + 1] = s2;
      }
    }
    __syncthreads();
    if (t < 16) {
      float s = 0.f, s2 = 0.f;
#pragma unroll
      for (int w = 0; w < 4; w++) { s += Pred[t * 8 + w * 2]; s2 += Pred[t * 8 + w * 2 + 1]; }
      float mean = s * (1.0f / 512.0f);
      float var  = s2 * (1.0f / 512.0f) - mean * mean;
      MV[t * 2]     = mean;
      MV[t * 2 + 1] = rsqrtf(var + 1e-5f);
    }
    __syncthreads();
    float lww[8], lbb_[8];
#pragma unroll
    for (int ni = 0; ni < 8; ni++) {
      lww[ni]  = lw[n0w + ni * 16 + lm];
      lbb_[ni] = lb[n0w + ni * 16 + lm];
    }
    if (z == 0) {
      // fold attn scale (1/sqrt(dh) * log2(e)) into q so attn does p=exp2(s) raw
      const float SC = 0.125f * 1.44269504088896f;
#pragma unroll
      for (int ni = 0; ni < 8; ni++) { lww[ni] *= SC; lbb_[ni] *= SC; }
    }
#pragma unroll
    for (int r = 0; r < 4; r++) {
      int row = quad * 4 + r;
      float mean = MV[row * 2], rstd = MV[row * 2 + 1];
      size_t obase = (size_t)(m0 + row) * 512 + n0w;
#pragma unroll
      for (int ni = 0; ni < 8; ni++)
        out[obase + ni * 16 + lm] =
            __float2bfloat16((acc[ni][r] - mean) * rstd * lww[ni] + lbb_[ni]);
    }
  } else {
    // ---------- g/v GEMM: m-tile 128, n-tile 64 (stride 72, 16-B aligned) ----------
    bf16* As = (bf16*)sm;                 // [128][72] = 18432 B
    bf16* Bs = (bf16*)(sm + 18432);       // [64][72]  = 9216 B
    const bf16* A    = (z == 3) ? fb : fa;
    const bf16* Wt   = (z == 3) ? Wvt : Wgt;
    const float* bias = (z == 3) ? bv : bg;
    int x = blockIdx.x;
    int m0 = (x >> 3) * 128, n0 = (x & 7) * 64;
    int wm = wave * 32;
    f32x4 acc[2][4] = {};
    for (int k0 = 0; k0 < 256; k0 += 64) {
      __syncthreads();
#pragma unroll
      for (int i = 0; i < 4; i++) {
        int id = t + 256 * i, r = id >> 3, cg = id & 7;
        *(ushort8_t*)(&As[r * 72 + cg * 8]) =
            *(const ushort8_t*)(A + (size_t)(m0 + r) * 256 + k0 + cg * 8);
      }
#pragma unroll
      for (int i = 0; i < 2; i++) {
        int id = t + 256 * i, r = id >> 3, cg = id & 7;
        *(ushort8_t*)(&Bs[r * 72 + cg * 8]) =
            *(const ushort8_t*)(Wt + (size_t)(n0 + r) * 256 + k0 + cg * 8);
      }
      __syncthreads();
#pragma unroll
      for (int kk = 0; kk < 64; kk += 32) {
        bf16x8 af[2], bf_[4];
#pragma unroll
        for (int mi = 0; mi < 2; mi++)
          af[mi] = *(const bf16x8*)(&As[(wm + mi * 16 + lm) * 72 + kk + q8]);
#pragma unroll
        for (int ni = 0; ni < 4; ni++)
          bf_[ni] = *(const bf16x8*)(&Bs[(ni * 16 + lm) * 72 + kk + q8]);
#pragma unroll
        for (int mi = 0; mi < 2; mi++)
#pragma unroll
          for (int ni = 0; ni < 4; ni++)
            acc[mi][ni] = MFMA32(af[mi], bf_[ni], acc[mi][ni]);
      }
    }
    if (z == 2) {
#pragma unroll
      for (int mi = 0; mi < 2; mi++)
#pragma unroll
        for (int ni = 0; ni < 4; ni++) {
          int nn = n0 + ni * 16 + lm;
          float bvv = bias[nn];
          int mb = m0 + wm + mi * 16 + quad * 4;
#pragma unroll
          for (int r = 0; r < 4; r++)
            gout[(size_t)(mb + r) * 512 + nn] = __float2bfloat16(acc[mi][ni][r] + bvv);
        }
    } else {
      // v^T: bounce through LDS [64 d][136] for coalesced [d][j] write
      __syncthreads();
      bf16* buf = (bf16*)sm;
#pragma unroll
      for (int mi = 0; mi < 2; mi++)
#pragma unroll
        for (int ni = 0; ni < 4; ni++) {
          int d_local = ni * 16 + lm;
          float bvv = bias[n0 + d_local];
          int j_local = wm + mi * 16 + quad * 4;
#pragma unroll
          for (int r = 0; r < 4; r++)
            buf[d_local * 136 + j_local + r] = __float2bfloat16(acc[mi][ni][r] + bvv);
        }
      __syncthreads();
      int bidx2 = m0 >> 11, j0g = m0 & 2047, hh = n0 >> 6;
      int dl = t >> 2, jseg = (t & 3) * 32;
      bf16* dstrow = vout + (size_t)((bidx2 * 8 + hh) * 64 + dl) * 2048 + j0g + jseg;
#pragma unroll
      for (int c = 0; c < 4; c++)
        *(ushort8_t*)(dstrow + c * 8) = *(const ushort8_t*)(&buf[dl * 136 + jseg + c * 8]);
    }
  }
}

// ---------------- flash attention: R4 structure + PV pipelined one iter behind ---
// 8 waves = (wj {0,1}: 32-j slice, wi 0..3: 16-i rows); ONE shared 64-j tile per
// iter, 32 iters, ONE barrier per iter (R4's proven schedule). NEW: iteration it
// computes QK/exp/pack for tile it but runs PV for tile it-1 from REGISTERS
// (pa_prev + 4 V-frags read last iter, before its barrier -> same dbuf hazard
// discipline). PV no longer waits on this iter's ds_reads: chain = max(QKpath,
// PV) instead of sum. Q frags direct from global (no Q LDS, LDS 37376 B).
// K sigma-permuted; P register-only; l on matrix pipe; XCD swizzle.
__global__ __launch_bounds__(512, 4) void attn_kernel(
    const bf16* __restrict__ q, const bf16* __restrict__ k,
    const bf16* __restrict__ vt, const bf16* __restrict__ g,
    const u64* __restrict__ mbits,
    bf16* __restrict__ gh, bf16* __restrict__ gl) {
  __shared__ __align__(16) char smem[37376];
  bf16* KVB = (bf16*)smem;               // 2 bufs x [K 64*72 | V 64*72] = 36864 B
  float* Om = (float*)smem;              // epilogue overlay: 64*66*4 = 16896 B
  float* Lbuf = (float*)(smem + 36864);  // 2*64 floats = 512 B
  constexpr int TILE = 64 * 72;
  constexpr int BUFE = 2 * TILE;

  // XCD-locality swizzle (proven in R4): each XCD owns 2 whole bh
  int flat = blockIdx.y * 32 + blockIdx.x;
  int bh = (flat & 7) * 2 + (flat >> 8);
  int qt = (flat >> 3) & 31;
  int bidx = bh >> 3, h = bh & 7;
  int i0 = qt * 64;
  int t = threadIdx.x, wave = t >> 6, lane = t & 63;
  int wj = wave >> 2, wi = wave & 3;
  int lm = lane & 15, quad = lane >> 4, q8 = quad * 8;
  int wj32 = wj * 32, wi16 = wi * 16;
  int srow = t >> 3, scg = (t & 7) * 8;  // staging: row 0..63, col-chunk 0..7

  // sigma-permuted K staging row (within each 32-row group)
  int sg = srow & 31;
  int ksrow = (srow & 32) + (((sg & 4) << 2) | ((sg & 24) >> 1) | (sg & 3));
  int ksl = ksrow * 72 + scg;
  int vsl = TILE + srow * 72 + scg;

  const bf16* kb = k + (size_t)(bidx * NB_) * INNER_ + h * DH_;
  const bf16* vb = vt + (size_t)(bh * DH_) * NB_;
  const bf16* ksrc = kb + (size_t)srow * INNER_ + scg;
  const bf16* vsrc = vb + (size_t)srow * NB_ + scg;

  // Q fragments direct from global (one-time; verified in R6)
  const bf16* qbase = q + (size_t)(bidx * NA_ + i0 + wi16 + lm) * INNER_ + h * DH_;
  bf16x8 bq0 = *(const bf16x8*)(qbase + q8);
  bf16x8 bq1 = *(const bf16x8*)(qbase + 32 + q8);

  // constant B fragment: ones-column at n=0 (bf16 1.0 = 0x3F80)
  bf16x8 bone;
  {
    short onev = (lm == 0) ? (short)0x3F80 : (short)0;
#pragma unroll
    for (int i = 0; i < 8; i++) bone[i] = onev;
  }

  f32x4 oacc[4] = {};
  f32x4 lacc = {};  // l at lanes lm==0, i_local = quad*4+r

  const u64* mrp = mbits + (size_t)(bidx * NA_ + i0 + wi16 + lm) * (NB_ / 64);
  int shp = wj32 + quad * 8;

  // prologue: tile0 -> buf0; tile1 -> regs
  ushort8_t kr = *(const ushort8_t*)(ksrc);
  ushort8_t vr = *(const ushort8_t*)(vsrc);
  *(ushort8_t*)(&KVB[ksl]) = kr;
  *(ushort8_t*)(&KVB[vsl]) = vr;
  kr = *(const ushort8_t*)(ksrc + (size_t)64 * INNER_);
  vr = *(const ushort8_t*)(vsrc + 64);
  u64 smw = mrp[0] >> shp;
  __syncthreads();  // buf0 ready

  bf16x8 paP, vP0, vP1, vP2, vP3;  // previous tile's P fragment + V fragments

  // ---- iteration 0 (peeled: QK/exp/pack + V-read, no PV yet) ----
  {
    bf16* Ks = KVB;
    bf16* Vs = KVB + TILE;
    bf16* Kn = KVB + BUFE;
    *(ushort8_t*)(&Kn[ksl]) = kr;
    *(ushort8_t*)(&Kn[vsl]) = vr;
    kr = *(const ushort8_t*)(ksrc + (size_t)128 * INNER_);
    vr = *(const ushort8_t*)(vsrc + 128);
    u64 nm = mrp[1] >> shp;

    bf16x8 a00 = *(const bf16x8*)(&Ks[(wj32 + lm) * 72 + q8]);
    bf16x8 a01 = *(const bf16x8*)(&Ks[(wj32 + lm) * 72 + 32 + q8]);
    bf16x8 a10 = *(const bf16x8*)(&Ks[(wj32 + 16 + lm) * 72 + q8]);
    bf16x8 a11 = *(const bf16x8*)(&Ks[(wj32 + 16 + lm) * 72 + 32 + q8]);
    f32x4 st0 = {0.f, 0.f, 0.f, 0.f}, st1 = {0.f, 0.f, 0.f, 0.f};
    st0 = MFMA32(a00, bq0, st0);
    st0 = MFMA32(a01, bq1, st0);
    st1 = MFMA32(a10, bq0, st1);
    st1 = MFMA32(a11, bq1, st1);

    float p0[4], p1[4];
#pragma unroll
    for (int r = 0; r < 4; r++) {
      p0[r] = EXP2(((smw >> r) & 1ull) ? st0[r] : -200.0f);
      p1[r] = EXP2(((smw >> (4 + r)) & 1ull) ? st1[r] : -200.0f);
    }
    uint4_t u0;
    u0[0] = pkbf(p0[0], p0[1]);
    u0[1] = pkbf(p0[2], p0[3]);
    u0[2] = pkbf(p1[0], p1[1]);
    u0[3] = pkbf(p1[2], p1[3]);
    paP = __builtin_bit_cast(bf16x8, u0);

    vP0 = *(const bf16x8*)(&Vs[(0 * 16 + lm) * 72 + wj32 + q8]);
    vP1 = *(const bf16x8*)(&Vs[(1 * 16 + lm) * 72 + wj32 + q8]);
    vP2 = *(const bf16x8*)(&Vs[(2 * 16 + lm) * 72 + wj32 + q8]);
    vP3 = *(const bf16x8*)(&Vs[(3 * 16 + lm) * 72 + wj32 + q8]);

    smw = nm;
    __syncthreads();
  }

  for (int it = 1; it < 32; it++) {
    bf16* Ks = KVB + (it & 1) * BUFE;
    bf16* Vs = Ks + TILE;
    // write next tile into alt buffer (off critical path)
    if (it < 31) {
      bf16* Kn = KVB + ((it + 1) & 1) * BUFE;
      *(ushort8_t*)(&Kn[ksl]) = kr;
      *(ushort8_t*)(&Kn[vsl]) = vr;
    }
    // issue global loads 2 tiles ahead
    if (it < 30) {
      kr = *(const ushort8_t*)(ksrc + (size_t)(it + 2) * (64 * INNER_));
      vr = *(const ushort8_t*)(vsrc + (it + 2) * 64);
    }
    u64 nm = (it < 31) ? (mrp[it + 1] >> shp) : 0;

    // PV for tile it-1 (register-only; independent of this iter's ds_reads)
    oacc[0] = MFMA32(paP, vP0, oacc[0]);
    oacc[1] = MFMA32(paP, vP1, oacc[1]);
    oacc[2] = MFMA32(paP, vP2, oacc[2]);
    oacc[3] = MFMA32(paP, vP3, oacc[3]);
    lacc = MFMA32(paP, bone, lacc);

    // QK^T for tile it: wave's 32-j slice (sigma-permuted rows)
    bf16x8 a00 = *(const bf16x8*)(&Ks[(wj32 + lm) * 72 + q8]);
    bf16x8 a01 = *(const bf16x8*)(&Ks[(wj32 + lm) * 72 + 32 + q8]);
    bf16x8 a10 = *(const bf16x8*)(&Ks[(wj32 + 16 + lm) * 72 + q8]);
    bf16x8 a11 = *(const bf16x8*)(&Ks[(wj32 + 16 + lm) * 72 + 32 + q8]);
    f32x4 st0 = {0.f, 0.f, 0.f, 0.f}, st1 = {0.f, 0.f, 0.f, 0.f};
    st0 = MFMA32(a00, bq0, st0);
    st0 = MFMA32(a01, bq1, st0);
    st1 = MFMA32(a10, bq0, st1);
    st1 = MFMA32(a11, bq1, st1);

    // V fragments for tile it (consumed next iteration)
    bf16x8 vC0 = *(const bf16x8*)(&Vs[(0 * 16 + lm) * 72 + wj32 + q8]);
    bf16x8 vC1 = *(const bf16x8*)(&Vs[(1 * 16 + lm) * 72 + wj32 + q8]);
    bf16x8 vC2 = *(const bf16x8*)(&Vs[(2 * 16 + lm) * 72 + wj32 + q8]);
    bf16x8 vC3 = *(const bf16x8*)(&Vs[(3 * 16 + lm) * 72 + wj32 + q8]);

    // p = exp2(masked s); lane's j = wj32 + quad*8 + js*4 + r -> bit js*4+r
    float p0[4], p1[4];
#pragma unroll
    for (int r = 0; r < 4; r++) {
      p0[r] = EXP2(((smw >> r) & 1ull) ? st0[r] : -200.0f);
      p1[r] = EXP2(((smw >> (4 + r)) & 1ull) ? st1[r] : -200.0f);
    }
    uint4_t u0;
    u0[0] = pkbf(p0[0], p0[1]);
    u0[1] = pkbf(p0[2], p0[3]);
    u0[2] = pkbf(p1[0], p1[1]);
    u0[3] = pkbf(p1[2], p1[3]);
    paP = __builtin_bit_cast(bf16x8, u0);
    vP0 = vC0; vP1 = vC1; vP2 = vC2; vP3 = vC3;

    smw = nm;
    __syncthreads();  // alt-buffer writes visible; current reads done
  }

  // final PV for tile 31 (registers)
  oacc[0] = MFMA32(paP, vP0, oacc[0]);
  oacc[1] = MFMA32(paP, vP1, oacc[1]);
  oacc[2] = MFMA32(paP, vP2, oacc[2]);
  oacc[3] = MFMA32(paP, vP3, oacc[3]);
  lacc = MFMA32(paP, bone, lacc);

  // -------- epilogue: 2-way merge (wj partners) + distributed write --------
  if (lm == 0) {
#pragma unroll
    for (int r = 0; r < 4; r++)
      Lbuf[wj * 64 + wi16 + quad * 4 + r] = lacc[r];
  }
  if (wj == 1) {
#pragma unroll
    for (int c = 0; c < 4; c++)
#pragma unroll
      for (int r = 0; r < 4; r++)
        Om[(wi16 + quad * 4 + r) * 66 + c * 16 + lm] = oacc[c][r];
  }
  __syncthreads();
  if (wj == 0) {
#pragma unroll
    for (int c = 0; c < 4; c++)
#pragma unroll
      for (int r = 0; r < 4; r++)
        Om[(wi16 + quad * 4 + r) * 66 + c * 16 + lm] += oacc[c][r];
  }
  __syncthreads();
  // final write: wave w -> rows w*8..w*8+7; thread: 8 consecutive cols
  {
    int row = wave * 8 + (lane >> 3);
    int col = (lane & 7) * 8;
    float l = Lbuf[row] + Lbuf[64 + row];
    float inv = 1.0f / l;
    size_t idx = (size_t)(bidx * NA_ + i0 + row) * INNER_ + h * DH_ + col;
    ushort8_t gv = *(const ushort8_t*)(g + idx);
    ushort8_t oh, ol;
#pragma unroll
    for (int e = 0; e < 8; e++) {
      float o = Om[row * 66 + col + e];
      float gf = b2f((unsigned short)gv[e]);
      float sig = 1.0f / (1.0f + __expf(-gf));
      float val = o * inv * sig;
      unsigned short hb = bfbits(val);
      oh[e] = hb;
      ol[e] = bfbits(val - b2f(hb));
    }
    *(ushort8_t*)(gh + idx) = oh;
    *(ushort8_t*)(gl + idx) = ol;
  }
}

// ---------------- final GEMM in split-bf16 (hi/lo), 32x64 tiles, fp32 out -------
__global__ __launch_bounds__(256) void gemm_split_kernel(
    const bf16* __restrict__ Ah, const bf16* __restrict__ Al,
    const bf16* __restrict__ Bh, const bf16* __restrict__ Bl,
    const float* __restrict__ bias, float* __restrict__ C) {
  constexpr int K = 512, N = 256;
  __shared__ __align__(16) bf16 Ash[32 * 72];
  __shared__ __align__(16) bf16 Asl[32 * 72];
  __shared__ __align__(16) bf16 Bsh[64 * 72];
  __shared__ __align__(16) bf16 Bsl[64 * 72];
  int n0 = blockIdx.x * 64, m0 = blockIdx.y * 32;
  int t = threadIdx.x, wave = t >> 6, lane = t & 63;
  int lm = lane & 15, quad = lane >> 4, q8 = quad * 8;
  int wm = (wave & 1) * 16, wn = (wave >> 1) * 32;
  f32x4 acc[2] = {};
  for (int k0 = 0; k0 < K; k0 += 64) {
    __syncthreads();
    {
      int r = t >> 3, cg = t & 7;
      size_t ga = (size_t)(m0 + r) * K + k0 + cg * 8;
      *(ushort8_t*)(&Ash[r * 72 + cg * 8]) = *(const ushort8_t*)(Ah + ga);
      *(ushort8_t*)(&Asl[r * 72 + cg * 8]) = *(const ushort8_t*)(Al + ga);
    }
#pragma unroll
    for (int i = 0; i < 2; i++) {
      int id = t + 256 * i, r = id >> 3, cg = id & 7;
      size_t gb = (size_t)(n0 + r) * K + k0 + cg * 8;
      *(ushort8_t*)(&Bsh[r * 72 + cg * 8]) = *(const ushort8_t*)(Bh + gb);
      *(ushort8_t*)(&Bsl[r * 72 + cg * 8]) = *(const ushort8_t*)(Bl + gb);
    }
    __syncthreads();
#pragma unroll
    for (int kk = 0; kk < 64; kk += 32) {
      bf16x8 ah = *(const bf16x8*)(&Ash[(wm + lm) * 72 + kk + q8]);
      bf16x8 al = *(const bf16x8*)(&Asl[(wm + lm) * 72 + kk + q8]);
#pragma unroll
      for (int ni = 0; ni < 2; ni++) {
        bf16x8 bh_ = *(const bf16x8*)(&Bsh[(wn + ni * 16 + lm) * 72 + kk + q8]);
        bf16x8 bl_ = *(const bf16x8*)(&Bsl[(wn + ni * 16 + lm) * 72 + kk + q8]);
        acc[ni] = MFMA32(ah, bh_, acc[ni]);
        acc[ni] = MFMA32(ah, bl_, acc[ni]);
        acc[ni] = MFMA32(al, bh_, acc[ni]);
      }
    }
  }
#pragma unroll
  for (int ni = 0; ni < 2; ni++) {
    int n = n0 + wn + ni * 16 + lm;
    float bvv = bias[n];
    int mb = m0 + wm + quad * 4;
#pragma unroll
    for (int r = 0; r < 4; r++) C[(size_t)(mb + r) * N + n] = acc[ni][r] + bvv;
  }
}

extern "C" void kernel_launch(void* const* d_in, const int* in_sizes, int n_in,
                              void* d_out, int out_size, void* d_ws, size_t ws_size,
                              hipStream_t stream) {
  const float* feat_a = (const float*)d_in[0];
  const float* feat_b = (const float*)d_in[1];
  const void*  mask   = d_in[2];
  const float* Wq = (const float*)d_in[3];
  const float* bq = (const float*)d_in[4];
  const float* Wk = (const float*)d_in[5];
  const float* bk = (const float*)d_in[6];
  const float* Wv = (const float*)d_in[7];
  const float* bv = (const float*)d_in[8];
  const float* Wg = (const float*)d_in[9];
  const float* bg = (const float*)d_in[10];
  const float* Wo = (const float*)d_in[11];
  const float* bo = (const float*)d_in[12];
  const float* law = (const float*)d_in[13];
  const float* lab = (const float*)d_in[14];
  const float* lbw = (const float*)d_in[15];
  const float* lbb = (const float*)d_in[16];
  const float* qlw = (const float*)d_in[17];
  const float* qlb = (const float*)d_in[18];
  const float* klw = (const float*)d_in[19];
  const float* klb = (const float*)d_in[20];

  char* ws = (char*)d_ws;
  size_t off = 0;
  auto alloc = [&](size_t bytes) -> void* {
    void* p = ws + off;
    off += (bytes + 255) & ~(size_t)255;
    return p;
  };
  bf16* fa    = (bf16*)alloc((size_t)MROWS * 256 * 2);
  bf16* fb    = (bf16*)alloc((size_t)MROWS * 256 * 2);
  bf16* Wqt   = (bf16*)alloc((size_t)131072 * 2);
  bf16* Wkt   = (bf16*)alloc((size_t)131072 * 2);
  bf16* Wvt   = (bf16*)alloc((size_t)131072 * 2);
  bf16* Wgt   = (bf16*)alloc((size_t)131072 * 2);
  bf16* Woth  = (bf16*)alloc((size_t)131072 * 2);
  bf16* Wotl  = (bf16*)alloc((size_t)131072 * 2);
  bf16* qb_   = (bf16*)alloc((size_t)MROWS * 512 * 2);
  bf16* kb_   = (bf16*)alloc((size_t)MROWS * 512 * 2);
  bf16* vtb   = (bf16*)alloc((size_t)1024 * 2048 * 2);
  bf16* gbuf  = (bf16*)alloc((size_t)MROWS * 512 * 2);
  bf16* gh    = (bf16*)alloc((size_t)MROWS * 512 * 2);
  bf16* gl    = (bf16*)alloc((size_t)MROWS * 512 * 2);
  u64*  mbits = (u64*)alloc((size_t)131072 * 8);

  prep_kernel<<<6656, 256, 0, stream>>>(
      feat_a, feat_b, law, lab, lbw, lbb, fa, fb,
      Wq, Wk, Wv, Wg, Wo, Wqt, Wkt, Wvt, Wgt, Woth, Wotl, mask, mbits);
  gemm4_kernel<<<dim3(256, 1, 4), 256, 0, stream>>>(
      fa, fb, Wqt, Wkt, Wgt, Wvt, bq, bk, bg, bv,
      qlw, qlb, klw, klb, qb_, kb_, gbuf, vtb);
  attn_kernel<<<dim3(32, 16), 512, 0, stream>>>(qb_, kb_, vtb, gbuf, mbits, gh, gl);
  gemm_split_kernel<<<dim3(4, 128), 256, 0, stream>>>(gh, gl, Woth, Wotl, bo, (float*)d_out);
}